// Round 11
// baseline (5064.412 us; speedup 1.0000x reference)
//
#include <hip/hip_runtime.h>
#include <math.h>

typedef float f4x __attribute__((ext_vector_type(4)));
typedef short s8v __attribute__((ext_vector_type(8)));
typedef _Float16 h2v __attribute__((ext_vector_type(2)));
typedef _Float16 h8v __attribute__((ext_vector_type(8)));
typedef unsigned short ushort_;

#define B_    128
#define T_ENC 40
#define T_DEC 27
#define T_ALL 67
#define HID_  512
#define G3_   1536
#define EMB_  1024
#define V_    20000
#define NBLK  1024           // 128 unit-groups x 8 batch-groups(16 b) -> 4 blocks/CU
#define WP    260            // LDS weight row pitch in h2v units (256 + 4 pad)

__device__ __forceinline__ float sigmoidf_(float x) { return 1.f / (1.f + expf(-x)); }

__device__ __forceinline__ ushort_ f2bf(float f) {   // RNE fp32 -> bf16
  unsigned u = __float_as_uint(f);
  return (ushort_)((u + 0x7FFFu + ((u >> 16) & 1u)) >> 16);
}

__device__ __forceinline__ float fdot2_(h2v a, h2v b, float c) {
#if __has_builtin(__builtin_amdgcn_fdot2)
  return __builtin_amdgcn_fdot2(a, b, c, false);
#else
  return c + (float)a[0] * (float)b[0] + (float)a[1] * (float)b[1];
#endif
}

union hld { h8v v8; h2v p[4]; };

// ------- per-GROUP barrier: 8 independent groups of 128 blocks (4 leaves x 32 + root each) -------
__device__ __forceinline__ void gbar(unsigned* bars, unsigned barno, int grp, int wb) {
  __syncthreads();
  if (threadIdx.x == 0) {
    __threadfence();  // release our h writes
    unsigned* base = bars + (size_t)grp * 256;   // 1 KB per group
    unsigned* leaf = base + (wb >> 5) * 32;      // 4 leaves (32 blocks each), 128 B apart
    unsigned* root = base + 128;
    unsigned* gen  = base + 160;
    if (__hip_atomic_fetch_add(leaf, 1u, __ATOMIC_RELAXED, __HIP_MEMORY_SCOPE_AGENT) == barno * 32u - 1u) {
      if (__hip_atomic_fetch_add(root, 1u, __ATOMIC_RELAXED, __HIP_MEMORY_SCOPE_AGENT) == barno * 4u - 1u) {
        __hip_atomic_store(gen, barno, __ATOMIC_RELEASE, __HIP_MEMORY_SCOPE_AGENT);
      }
    }
    while (__hip_atomic_load(gen, __ATOMIC_RELAXED, __HIP_MEMORY_SCOPE_AGENT) < barno) {
      __builtin_amdgcn_s_sleep(1);
    }
    __threadfence();  // acquire before reading group peers' h
  }
  __syncthreads();
}

// ---------------- gather decoder word embeddings ----------------
__global__ __launch_bounds__(128) void k_gather(const int* __restrict__ target,
                                                const float* __restrict__ E,
                                                float* __restrict__ words) {
  int m = blockIdx.x;
  int b = m / T_DEC, t = m % T_DEC;
  int idx = target[b * 28 + t];
  const float4* src = reinterpret_cast<const float4*>(E + (size_t)idx * HID_);
  float4* dst = reinterpret_cast<float4*>(words + (size_t)m * HID_);
  dst[threadIdx.x] = src[threadIdx.x];
}

// ---------------- fp32 -> bf16 convert (W_out), 8 elems/thread ----------------
__global__ __launch_bounds__(256) void k_cvtw(const float* __restrict__ src, ushort_* __restrict__ dst) {
  size_t i = ((size_t)blockIdx.x * 256 + threadIdx.x) * 8;
  f4x a = *reinterpret_cast<const f4x*>(&src[i]);
  f4x b = *reinterpret_cast<const f4x*>(&src[i + 4]);
  s8v o;
#pragma unroll
  for (int j = 0; j < 4; ++j) { o[j] = (short)f2bf(a[j]); o[4 + j] = (short)f2bf(b[j]); }
  *reinterpret_cast<s8v*>(&dst[i]) = o;
}

// ---------------- fp32 GEMM, transposed scatter-store: Ct[(t*1536+n)*128 + b], m = b*TT+t ----
__global__ __launch_bounds__(256) void k_gemm_t(const float* __restrict__ A, int lda,
                                                const float* __restrict__ Bm, int ldb, int boff,
                                                const float* __restrict__ bias,
                                                float* __restrict__ Ct, int TT, int K) {
  __shared__ float As[16][128];
  __shared__ float Bs[16][128];
  const int tid = threadIdx.x;
  const int m0 = blockIdx.y * 128;
  const int n0 = blockIdx.x * 128;
  const int tx = tid & 15, ty = tid >> 4;
  float acc[8][8];
#pragma unroll
  for (int i = 0; i < 8; ++i)
#pragma unroll
    for (int j = 0; j < 8; ++j) acc[i][j] = 0.f;

  for (int k0 = 0; k0 < K; k0 += 16) {
#pragma unroll
    for (int i = 0; i < 2; ++i) {
      int v = tid * 2 + i;
      int row = v >> 2;
      int kv = (v & 3) << 2;
      float4 a4 = *reinterpret_cast<const float4*>(&A[(size_t)(m0 + row) * lda + k0 + kv]);
      As[kv + 0][row] = a4.x; As[kv + 1][row] = a4.y; As[kv + 2][row] = a4.z; As[kv + 3][row] = a4.w;
      float4 b4 = *reinterpret_cast<const float4*>(&Bm[(size_t)(n0 + row) * ldb + boff + k0 + kv]);
      Bs[kv + 0][row] = b4.x; Bs[kv + 1][row] = b4.y; Bs[kv + 2][row] = b4.z; Bs[kv + 3][row] = b4.w;
    }
    __syncthreads();
#pragma unroll
    for (int kk = 0; kk < 16; ++kk) {
      float a[8], bb[8];
      *reinterpret_cast<float4*>(&a[0]) = *reinterpret_cast<const float4*>(&As[kk][ty * 8]);
      *reinterpret_cast<float4*>(&a[4]) = *reinterpret_cast<const float4*>(&As[kk][ty * 8 + 4]);
      *reinterpret_cast<float4*>(&bb[0]) = *reinterpret_cast<const float4*>(&Bs[kk][tx * 8]);
      *reinterpret_cast<float4*>(&bb[4]) = *reinterpret_cast<const float4*>(&Bs[kk][tx * 8 + 4]);
#pragma unroll
      for (int i = 0; i < 8; ++i)
#pragma unroll
        for (int j = 0; j < 8; ++j) acc[i][j] += a[i] * bb[j];
    }
    __syncthreads();
  }
#pragma unroll
  for (int i = 0; i < 8; ++i) {
    int m = m0 + ty * 8 + i;
    int b = m / TT, tt = m - b * TT;
    float* cp = &Ct[((size_t)tt * G3_ + n0 + tx * 8) * 128 + b];
#pragma unroll
    for (int j = 0; j < 8; ++j) cp[(size_t)j * 128] = acc[i][j] + bias[n0 + tx * 8 + j];
  }
}

// ---------------- persistent recurrence: fp16 dot2, 8 batch-groups of 16 b, 4 blocks/CU ----------------
// 1024 blocks: grp = bid&7 (batches [grp*16,+16)), wb = bid>>3 (4 units). 16 waves/CU.
// h circulates as fp32 [u][b] (state) + packed-fp16 [k/2][b] (matmul operand), both ping-ponged.
__global__ __launch_bounds__(256, 4) void k_recur(
    const float* __restrict__ G1t, const float* __restrict__ GWt,
    const float* __restrict__ W_hh1, const float* __restrict__ W_ih2, const float* __restrict__ W_hh2,
    const float* __restrict__ b_hh1, const float* __restrict__ b_hh2,
    const float* __restrict__ b_ih1, const float* __restrict__ b_ih2,
    float* h1x, float* h1y, float* h2x, float* h2y,
    h2v* hp1x, h2v* hp1y, h2v* hp2x, h2v* hp2y,
    float* __restrict__ h2seqT, unsigned* bars) {
  __shared__ h2v Wl[36 * WP];       // fp16 pairs; rows: mat*12 + g*4 + wid
  __shared__ float S1[4][16];       // h1_new exchange (u-wave -> pair-pack)
  __shared__ float S2[4][16];       // h2_new exchange

  const int tid = threadIdx.x;
  const int bid = blockIdx.x;
  const int grp = bid & 7;
  const int wb  = bid >> 3;
  const int u0 = wb * 4;
  const int bbase = grp * 16;
  const int wid = tid >> 6;          // wave owns unit u0+wid
  const int lane = tid & 63;
  const int kq = lane >> 2;          // k-slice 0..15 (reduced over)
  const int cc = lane & 3;           // b-quad within 16-b group
  const int ugl = u0 + wid;
  const int gb = bbase + cc * 4;
  const int myb = gb + (kq & 3);     // keeper lane (kq<4) owns this b

  // ---- pin fp16 weights in LDS (once) ----
  for (int idx = tid; idx < 36 * 128; idx += 256) {
    int row = idx >> 7; int c4 = (idx & 127) << 2;
    int mm = row / 12, rem = row - mm * 12; int g = rem >> 2, ur = rem & 3;
    int grow = g * HID_ + u0 + ur;
    const float* src = (mm == 0) ? (W_hh1 + (size_t)grow * HID_ + c4)
                     : (mm == 1) ? (W_ih2 + (size_t)grow * EMB_ + c4)
                                 : (W_hh2 + (size_t)grow * HID_ + c4);
    f4x w4 = *reinterpret_cast<const f4x*>(src);
    h2v p0; p0[0] = (_Float16)w4[0]; p0[1] = (_Float16)w4[1];
    h2v p1; p1[0] = (_Float16)w4[2]; p1[1] = (_Float16)w4[3];
    Wl[row * WP + (c4 >> 1)] = p0;
    Wl[row * WP + (c4 >> 1) + 1] = p1;
  }
  const float bh1r = b_hh1[ugl], bh1z = b_hh1[HID_ + ugl], bh1n = b_hh1[2 * HID_ + ugl];
  const float bh2r = b_hh2[ugl], bh2z = b_hh2[HID_ + ugl], bh2n = b_hh2[2 * HID_ + ugl];
  const float bi1r = b_ih1[ugl], bi1z = b_ih1[HID_ + ugl], bi1n = b_ih1[2 * HID_ + ugl];
  const float bi2r = b_ih2[ugl], bi2z = b_ih2[HID_ + ugl], bi2n = b_ih2[2 * HID_ + ugl];
  __syncthreads();

  // ---- prologue: h1[1] = GRU1(h1=0, x0): gh1 = bias only; produce f32 state + fp16 pairs ----
  {
    float h1v = 0.f;
    if (kq < 4) {
      float gr = G1t[(size_t)ugl * 128 + myb];
      float gz = G1t[(size_t)(HID_ + ugl) * 128 + myb];
      float gn = G1t[(size_t)(2 * HID_ + ugl) * 128 + myb];
      float r = sigmoidf_(gr + bh1r);
      float z = sigmoidf_(gz + bh1z);
      float n = tanhf(gn + r * bh1n);
      h1v = (1.f - z) * n;
      h1x[(size_t)ugl * 128 + myb] = h1v;
      S1[wid][cc * 4 + kq] = h1v;
    }
    __syncthreads();
    if (tid < 32) {
      int pi = tid >> 4, b = tid & 15;
      h2v pr; pr[0] = (_Float16)S1[2 * pi][b]; pr[1] = (_Float16)S1[2 * pi + 1][b];
      hp1x[((size_t)(u0 >> 1) + pi) * 128 + bbase + b] = pr;
    }
  }
  gbar(bars, 1u, grp, wb);

  for (int p = 0; p < T_ALL; ++p) {
    const float* h1cur = (p & 1) ? h1y : h1x;
    float*       h1nxt = (p & 1) ? h1x : h1y;
    const float* h2cur = (p & 1) ? h2y : h2x;
    float*       h2nxt = (p & 1) ? h2x : h2y;
    const h2v* hp1cur = (p & 1) ? hp1y : hp1x;
    h2v*       hp1nxt = (p & 1) ? hp1x : hp1y;
    const h2v* hp2cur = (p & 1) ? hp2y : hp2x;
    h2v*       hp2nxt = (p & 1) ? hp2x : hp2y;

    // gate + prev-state prefetch (independent of matmul loads)
    float a_gr, a_gz, a_gn, b_xr, b_xz, b_xn;
    if (p + 1 < T_ENC) {
      const float* gp = G1t + (size_t)(p + 1) * (G3_ * 128);
      a_gr = gp[(size_t)ugl * 128 + myb];
      a_gz = gp[(size_t)(HID_ + ugl) * 128 + myb];
      a_gn = gp[(size_t)(2 * HID_ + ugl) * 128 + myb];
    } else { a_gr = bi1r; a_gz = bi1z; a_gn = bi1n; }
    if (p < T_ENC) { b_xr = bi2r; b_xz = bi2z; b_xn = bi2n; }
    else {
      const float* gp = GWt + (size_t)(p - T_ENC) * (G3_ * 128);
      b_xr = gp[(size_t)ugl * 128 + myb];
      b_xz = gp[(size_t)(HID_ + ugl) * 128 + myb];
      b_xn = gp[(size_t)(2 * HID_ + ugl) * 128 + myb];
    }
    const float h1p = h1cur[(size_t)ugl * 128 + myb];
    const float h2p = h2cur[(size_t)ugl * 128 + myb];

    float acc[4][3][3];   // [e = b&3][mat][gate]
#pragma unroll
    for (int e = 0; e < 4; ++e)
#pragma unroll
      for (int mm = 0; mm < 3; ++mm)
#pragma unroll
        for (int g = 0; g < 3; ++g) acc[e][mm][g] = 0.f;

    hld A1[4], A2[4], B1[4], B2[4], C1[4], C2[4];

    // chunk = 128 k = 64 pairs; lane's 4 pairs = c*64 + kq*4 + j
#define LOADH(P1, P2, c) do { _Pragma("unroll") for (int j_ = 0; j_ < 4; ++j_) { \
      P1[j_].v8 = *reinterpret_cast<const h8v*>(&hp1cur[((size_t)(c) * 64 + kq * 4 + j_) * 128 + gb]); \
      P2[j_].v8 = *reinterpret_cast<const h8v*>(&hp2cur[((size_t)(c) * 64 + kq * 4 + j_) * 128 + gb]); } } while (0)

#define FMAC(c, P1, P2) do { hld w_[9]; \
      _Pragma("unroll") for (int r_ = 0; r_ < 9; ++r_) { int mm_ = r_ / 3, gg_ = r_ - mm_ * 3; \
        w_[r_].v8 = *reinterpret_cast<const h8v*>(&Wl[(mm_ * 12 + gg_ * 4 + wid) * WP + (c) * 64 + kq * 4]); } \
      _Pragma("unroll") for (int j_ = 0; j_ < 4; ++j_) \
        _Pragma("unroll") for (int e_ = 0; e_ < 4; ++e_) \
          _Pragma("unroll") for (int gg_ = 0; gg_ < 3; ++gg_) { \
            acc[e_][0][gg_] = fdot2_(P1[j_].p[e_], w_[gg_].p[j_],     acc[e_][0][gg_]); \
            acc[e_][1][gg_] = fdot2_(P1[j_].p[e_], w_[3 + gg_].p[j_], acc[e_][1][gg_]); \
            acc[e_][2][gg_] = fdot2_(P2[j_].p[e_], w_[6 + gg_].p[j_], acc[e_][2][gg_]); } } while (0)

    // software pipeline: depth-3 lookahead over 4 chunks, static buffer rotation
    LOADH(A1, A2, 0); LOADH(B1, B2, 1); LOADH(C1, C2, 2);
    FMAC(0, A1, A2); LOADH(A1, A2, 3);
    FMAC(1, B1, B2);
    FMAC(2, C1, C2);
    FMAC(3, A1, A2);
#undef LOADH
#undef FMAC

    // butterfly over kq lanes (lane bits 2..5); lane kq==e keeps b = gb+e
    float osel[3][3];
#pragma unroll
    for (int mm = 0; mm < 3; ++mm)
#pragma unroll
      for (int g = 0; g < 3; ++g) osel[mm][g] = 0.f;
#pragma unroll
    for (int e = 0; e < 4; ++e)
#pragma unroll
      for (int mm = 0; mm < 3; ++mm)
#pragma unroll
        for (int g = 0; g < 3; ++g) {
          float s = acc[e][mm][g];
          s += __shfl_xor(s, 4); s += __shfl_xor(s, 8); s += __shfl_xor(s, 16); s += __shfl_xor(s, 32);
          if (kq == e) osel[mm][g] = s;
        }

    float h1v = 0.f, h2vv = 0.f;
    if (kq < 4) {
      // A-combine: h1[p+2]  (t_A = p+1)
      if (p + 1 < T_ALL) {
        float r = sigmoidf_(a_gr + osel[0][0] + bh1r);
        float z = sigmoidf_(a_gz + osel[0][1] + bh1z);
        float n = tanhf(a_gn + r * (osel[0][2] + bh1n));
        h1v = (1.f - z) * n + z * h1p;
        h1nxt[(size_t)ugl * 128 + myb] = h1v;
      }
      // B-combine: h2[p+1]  (t_B = p)
      {
        float r = sigmoidf_(b_xr + osel[1][0] + osel[2][0] + bh2r);
        float z = sigmoidf_(b_xz + osel[1][1] + osel[2][1] + bh2z);
        float n = tanhf(b_xn + osel[1][2] + r * (osel[2][2] + bh2n));
        h2vv = (1.f - z) * n + z * h2p;
        h2nxt[(size_t)ugl * 128 + myb] = h2vv;
        if (p >= T_ENC)
          h2seqT[((size_t)(p - T_ENC) * HID_ + ugl) * 128 + myb] = h2vv;
      }
      S1[wid][cc * 4 + kq] = h1v;
      S2[wid][cc * 4 + kq] = h2vv;
    }
    __syncthreads();
    if (tid < 32) {           // pack h1[p+2] fp16 pairs
      int pi = tid >> 4, b = tid & 15;
      h2v pr; pr[0] = (_Float16)S1[2 * pi][b]; pr[1] = (_Float16)S1[2 * pi + 1][b];
      hp1nxt[((size_t)(u0 >> 1) + pi) * 128 + bbase + b] = pr;
    } else if (tid < 64) {    // pack h2[p+1] fp16 pairs
      int pi = (tid - 32) >> 4, b = tid & 15;
      h2v pr; pr[0] = (_Float16)S2[2 * pi][b]; pr[1] = (_Float16)S2[2 * pi + 1][b];
      hp2nxt[((size_t)(u0 >> 1) + pi) * 128 + bbase + b] = pr;
    }

    if (p + 1 < T_ALL) gbar(bars, 2u + (unsigned)p, grp, wb);
  }
}

// ---------------- pack: h2seqT fp32 [t][u][b] -> h2b bf16 [t][u>>3][b][u&7] (MFMA-B layout) ----------------
__global__ __launch_bounds__(256) void k_pack(const float* __restrict__ h2seqT,
                                              ushort_* __restrict__ h2b) {
  __shared__ ushort_ Ls[128][8];
  const int tid = threadIdx.x;
  const int kg = blockIdx.x;          // 0..63
  const int t  = blockIdx.y;          // 0..26
  const int e  = tid >> 5;            // 0..7 (u & 7)
  const int b4 = tid & 31;            // b-quad
  f4x v = *reinterpret_cast<const f4x*>(&h2seqT[((size_t)t * HID_ + kg * 8 + e) * 128 + b4 * 4]);
#pragma unroll
  for (int j = 0; j < 4; ++j) Ls[b4 * 4 + j][e] = f2bf(v[j]);
  __syncthreads();
  if (tid < 128) {
    *reinterpret_cast<s8v*>(&h2b[(((size_t)t * 64 + kg) * 128 + tid) * 8]) =
        *reinterpret_cast<const s8v*>(&Ls[tid][0]);
  }
}

// ---------------- projection: bf16 MFMA, C[m=v][n=b] = Wb(16x32 A) x h2b(32x16 B) ----------------
__global__ __launch_bounds__(256) void k_proj(const ushort_* __restrict__ Wb,
                                              const ushort_* __restrict__ h2b,
                                              const float* __restrict__ bias,
                                              float* __restrict__ out) {
  __shared__ ushort_ As[128 * 40];
  const int tid = threadIdx.x;
  const int t  = blockIdx.x;
  const int v0 = blockIdx.y * 128;
  const int lane = tid & 63;
  const int l15 = lane & 15, l4 = lane >> 4;
  const int wm = (tid >> 6) & 1, wn = tid >> 7;

  f4x acc[4][4];
#pragma unroll
  for (int i = 0; i < 4; ++i)
#pragma unroll
    for (int j = 0; j < 4; ++j) acc[i][j] = (f4x){0.f, 0.f, 0.f, 0.f};

  const int c0 = tid * 2, c1 = c0 + 1;
  const int sv0 = c0 >> 2, sk0 = c0 & 3;
  const int sv1 = c1 >> 2, sk1 = c1 & 3;
  s8v r0, r1;
  r0 = *reinterpret_cast<const s8v*>(&Wb[(size_t)(v0 + sv0) * HID_ + sk0 * 8]);
  r1 = *reinterpret_cast<const s8v*>(&Wb[(size_t)(v0 + sv1) * HID_ + sk1 * 8]);

  for (int ks = 0; ks < 16; ++ks) {
    __syncthreads();
    *reinterpret_cast<s8v*>(&As[sv0 * 40 + sk0 * 8]) = r0;
    *reinterpret_cast<s8v*>(&As[sv1 * 40 + sk1 * 8]) = r1;
    __syncthreads();
    if (ks < 15) {
      r0 = *reinterpret_cast<const s8v*>(&Wb[(size_t)(v0 + sv0) * HID_ + (ks + 1) * 32 + sk0 * 8]);
      r1 = *reinterpret_cast<const s8v*>(&Wb[(size_t)(v0 + sv1) * HID_ + (ks + 1) * 32 + sk1 * 8]);
    }
    s8v a[4], b[4];
#pragma unroll
    for (int mt = 0; mt < 4; ++mt)
      a[mt] = *reinterpret_cast<const s8v*>(&As[(wm * 64 + mt * 16 + l15) * 40 + l4 * 8]);
#pragma unroll
    for (int nt = 0; nt < 4; ++nt)
      b[nt] = *reinterpret_cast<const s8v*>(
          &h2b[(((size_t)t * 64 + ks * 4 + l4) * 128 + wn * 64 + nt * 16 + l15) * 8]);
#pragma unroll
    for (int mt = 0; mt < 4; ++mt)
#pragma unroll
      for (int nt = 0; nt < 4; ++nt)
        acc[mt][nt] = __builtin_amdgcn_mfma_f32_16x16x32_bf16(a[mt], b[nt], acc[mt][nt], 0, 0, 0);
  }

#pragma unroll
  for (int mt = 0; mt < 4; ++mt) {
    const int vb = v0 + wm * 64 + mt * 16 + l4 * 4;
    float bv[4];
    if (vb + 3 < V_) {
      *reinterpret_cast<f4x*>(bv) = *reinterpret_cast<const f4x*>(&bias[vb]);
    } else {
#pragma unroll
      for (int r = 0; r < 4; ++r) bv[r] = (vb + r < V_) ? bias[vb + r] : 0.f;
    }
#pragma unroll
    for (int nt = 0; nt < 4; ++nt) {
      const int bc = wn * 64 + nt * 16 + l15;
      float* cp = &out[((size_t)bc * T_DEC + t) * V_ + vb];
      if (vb + 3 < V_) {
        f4x o = acc[mt][nt];
        o[0] += bv[0]; o[1] += bv[1]; o[2] += bv[2]; o[3] += bv[3];
        *reinterpret_cast<f4x*>(cp) = o;
      } else {
#pragma unroll
        for (int r = 0; r < 4; ++r) if (vb + r < V_) cp[r] = acc[mt][nt][r] + bv[r];
      }
    }
  }
}

// ---------------- log-softmax over rows of 20000 (in place on d_out) ----------------
__global__ __launch_bounds__(256) void k_logsoftmax(float* __restrict__ out) {
  float* row = out + (size_t)blockIdx.x * V_;
  const int tid = threadIdx.x;
  float mx = -INFINITY, s = 0.f;
  for (int i = tid; i < V_; i += 256) {
    float x = row[i];
    if (x > mx) { s = s * expf(mx - x) + 1.f; mx = x; }
    else        { s += expf(x - mx); }
  }
#pragma unroll
  for (int o = 1; o < 64; o <<= 1) {
    float omx = __shfl_xor(mx, o);
    float os  = __shfl_xor(s, o);
    float M = fmaxf(mx, omx);
    s = s * expf(mx - M) + os * expf(omx - M);
    mx = M;
  }
  __shared__ float smx[4], ss[4];
  int wid = tid >> 6, lane = tid & 63;
  if (lane == 0) { smx[wid] = mx; ss[wid] = s; }
  __syncthreads();
  if (tid == 0) {
    float M = smx[0]; float S = ss[0];
#pragma unroll
    for (int w = 1; w < 4; ++w) {
      float M2 = fmaxf(M, smx[w]);
      S = S * expf(M - M2) + ss[w] * expf(smx[w] - M2);
      M = M2;
    }
    ss[0] = logf(S) + M;
  }
  __syncthreads();
  float lse = ss[0];
  for (int i = tid; i < V_; i += 256) row[i] -= lse;
}

// ---------------- host launch ----------------
extern "C" void kernel_launch(void* const* d_in, const int* in_sizes, int n_in,
                              void* d_out, int out_size, void* d_ws, size_t ws_size,
                              hipStream_t stream) {
  const float* input = (const float*)d_in[0];
  const int*   target = (const int*)d_in[1];
  const float* W_ih1 = (const float*)d_in[2];
  const float* W_hh1 = (const float*)d_in[3];
  const float* b_ih1 = (const float*)d_in[4];
  const float* b_hh1 = (const float*)d_in[5];
  const float* W_ih2 = (const float*)d_in[6];
  const float* W_hh2 = (const float*)d_in[7];
  const float* b_ih2 = (const float*)d_in[8];
  const float* b_hh2 = (const float*)d_in[9];
  const float* E     = (const float*)d_in[10];
  const float* W_out = (const float*)d_in[11];
  const float* b_out = (const float*)d_in[12];
  float* out = (float*)d_out;

  float* ws = (float*)d_ws;
  float* G1t    = ws; ws += (size_t)T_ENC * G3_ * 128;
  float* GWt    = ws; ws += (size_t)T_DEC * G3_ * 128;
  float* words  = ws; ws += (size_t)B_ * T_DEC * HID_;
  ushort_* Wb   = (ushort_*)ws; ws += (size_t)20096 * HID_ / 2;
  ushort_* h2b  = (ushort_*)ws; ws += (size_t)T_DEC * 64 * 128 * 8 / 2;
  float* h2seqT = ws; ws += (size_t)T_DEC * HID_ * 128;
  float* h1x = ws; ws += HID_ * 128;
  float* h1y = ws; ws += HID_ * 128;
  // ---- contiguous memset region: h2x (f32 state) + hp2x (fp16 pairs) + bars (8 groups) ----
  float* h2x = ws; ws += HID_ * 128;
  h2v* hp2x = (h2v*)ws; ws += HID_ / 2 * 128;
  unsigned* bars = (unsigned*)ws; ws += 2048;
  // ----
  float* h2y = ws; ws += HID_ * 128;
  h2v* hp1x = (h2v*)ws; ws += HID_ / 2 * 128;
  h2v* hp1y = (h2v*)ws; ws += HID_ / 2 * 128;
  h2v* hp2y = (h2v*)ws; ws += HID_ / 2 * 128;

  hipMemsetAsync(h2x, 0, ((size_t)HID_ * 128 + (size_t)HID_ / 2 * 128) * sizeof(float) + 8192, stream);

  k_gather<<<B_ * T_DEC, 128, 0, stream>>>(target, E, words);
  k_gemm_t<<<dim3(12, T_ENC), 256, 0, stream>>>(input, EMB_, W_ih1, EMB_, 0, b_ih1, G1t, T_ENC, EMB_);
  k_gemm_t<<<dim3(12, T_DEC), 256, 0, stream>>>(words, HID_, W_ih2, EMB_, HID_, b_ih2, GWt, T_DEC, HID_);
  k_cvtw<<<(V_ * HID_) / 2048, 256, 0, stream>>>(W_out, Wb);

  k_recur<<<NBLK, 256, 0, stream>>>(G1t, GWt, W_hh1, W_ih2, W_hh2, b_hh1, b_hh2, b_ih1, b_ih2,
                                    h1x, h1y, h2x, h2y, hp1x, hp1y, hp2x, hp2y, h2seqT, bars);
  k_pack<<<dim3(64, T_DEC), 256, 0, stream>>>(h2seqT, h2b);

  k_proj<<<dim3(T_DEC, (V_ + 127) / 128), 256, 0, stream>>>(Wb, h2b, b_out, out);
  k_logsoftmax<<<B_ * T_DEC, 256, 0, stream>>>(out);
}

// Round 12
// 2209.403 us; speedup vs baseline: 2.2922x; 2.2922x over previous
//
#include <hip/hip_runtime.h>
#include <math.h>

typedef float f4x __attribute__((ext_vector_type(4)));
typedef short s8v __attribute__((ext_vector_type(8)));
typedef short s4v __attribute__((ext_vector_type(4)));
typedef _Float16 h2v __attribute__((ext_vector_type(2)));
typedef _Float16 h8v __attribute__((ext_vector_type(8)));
typedef unsigned short ushort_;

#define B_    128
#define T_ENC 40
#define T_DEC 27
#define T_ALL 67
#define HID_  512
#define G3_   1536
#define EMB_  1024
#define V_    20000
#define NBLK  512            // 128 unit-groups x 4 batch-groups(32 b): 32-b slices keep 128B-line-aligned h writes (r11 lesson)
#define WP    260            // LDS weight row pitch in h2v units (256 + 4 pad)

__device__ __forceinline__ float sigmoidf_(float x) { return 1.f / (1.f + expf(-x)); }

__device__ __forceinline__ ushort_ f2bf(float f) {   // RNE fp32 -> bf16
  unsigned u = __float_as_uint(f);
  return (ushort_)((u + 0x7FFFu + ((u >> 16) & 1u)) >> 16);
}

__device__ __forceinline__ float fdot2_(h2v a, h2v b, float c) {
#if __has_builtin(__builtin_amdgcn_fdot2)
  return __builtin_amdgcn_fdot2(a, b, c, false);
#else
  return c + (float)a[0] * (float)b[0] + (float)a[1] * (float)b[1];
#endif
}

union hld { h8v v8; h2v p[4]; };

// ------- per-GROUP barrier: 4 independent groups of 128 blocks (4 leaves x 32 + root each) -------
__device__ __forceinline__ void gbar(unsigned* bars, unsigned barno, int grp, int wb) {
  __syncthreads();
  if (threadIdx.x == 0) {
    __threadfence();  // release our h writes
    unsigned* base = bars + (size_t)grp * 256;   // 1 KB per group
    unsigned* leaf = base + (wb >> 5) * 32;      // 4 leaves, 128 B apart
    unsigned* root = base + 128;
    unsigned* gen  = base + 160;
    if (__hip_atomic_fetch_add(leaf, 1u, __ATOMIC_RELAXED, __HIP_MEMORY_SCOPE_AGENT) == barno * 32u - 1u) {
      if (__hip_atomic_fetch_add(root, 1u, __ATOMIC_RELAXED, __HIP_MEMORY_SCOPE_AGENT) == barno * 4u - 1u) {
        __hip_atomic_store(gen, barno, __ATOMIC_RELEASE, __HIP_MEMORY_SCOPE_AGENT);
      }
    }
    while (__hip_atomic_load(gen, __ATOMIC_RELAXED, __HIP_MEMORY_SCOPE_AGENT) < barno) {
      __builtin_amdgcn_s_sleep(1);
    }
    __threadfence();  // acquire before reading group peers' h
  }
  __syncthreads();
}

// ---------------- gather decoder word embeddings -> bf16 rows m = b*27+t ----------------
__global__ __launch_bounds__(128) void k_gather(const int* __restrict__ target,
                                                const float* __restrict__ E,
                                                ushort_* __restrict__ wordsb) {
  int m = blockIdx.x;
  int b = m / T_DEC, t = m % T_DEC;
  int idx = target[b * 28 + t];
  f4x v = reinterpret_cast<const f4x*>(E + (size_t)idx * HID_)[threadIdx.x];
  s4v o;
#pragma unroll
  for (int j = 0; j < 4; ++j) o[j] = (short)f2bf(v[j]);
  reinterpret_cast<s4v*>(wordsb + (size_t)m * HID_)[threadIdx.x] = o;
}

// ---------------- generic fp32 -> bf16 convert, 8 elems/thread ----------------
__global__ __launch_bounds__(256) void k_cvt(const float* __restrict__ src, ushort_* __restrict__ dst) {
  size_t i = ((size_t)blockIdx.x * 256 + threadIdx.x) * 8;
  f4x a = *reinterpret_cast<const f4x*>(&src[i]);
  f4x b = *reinterpret_cast<const f4x*>(&src[i + 4]);
  s8v o;
#pragma unroll
  for (int j = 0; j < 4; ++j) { o[j] = (short)f2bf(a[j]); o[4 + j] = (short)f2bf(b[j]); }
  *reinterpret_cast<s8v*>(&dst[i]) = o;
}

// ---------------- bf16 MFMA GEMM, transposed scatter-store: Ct[(t*1536+n)*128 + b], m = b*TT+t ----
// A [M][lda] bf16 row-major, B [1536][ldb] bf16 row-major (col offset boff). Tile 128m x 128n, 4 waves 2x2.
__global__ __launch_bounds__(256) void k_mm(const ushort_* __restrict__ A, int lda,
                                            const ushort_* __restrict__ Bm, int ldb, int boff,
                                            const float* __restrict__ bias,
                                            float* __restrict__ Ct, int TT, int K) {
  const int tid = threadIdx.x;
  const int lane = tid & 63;
  const int l15 = lane & 15, l4 = lane >> 4;
  const int wm = (tid >> 6) & 1, wn = tid >> 7;
  const int m0 = blockIdx.y * 128;
  const int n0 = blockIdx.x * 128;

  f4x acc[4][4];
#pragma unroll
  for (int i = 0; i < 4; ++i)
#pragma unroll
    for (int j = 0; j < 4; ++j) acc[i][j] = (f4x){0.f, 0.f, 0.f, 0.f};

  for (int ks = 0; ks < K; ks += 32) {
    s8v a[4], b[4];
#pragma unroll
    for (int mt = 0; mt < 4; ++mt)
      a[mt] = *reinterpret_cast<const s8v*>(
          &A[(size_t)(m0 + wm * 64 + mt * 16 + l15) * lda + ks + l4 * 8]);
#pragma unroll
    for (int nt = 0; nt < 4; ++nt)
      b[nt] = *reinterpret_cast<const s8v*>(
          &Bm[(size_t)(n0 + wn * 64 + nt * 16 + l15) * ldb + boff + ks + l4 * 8]);
#pragma unroll
    for (int mt = 0; mt < 4; ++mt)
#pragma unroll
      for (int nt = 0; nt < 4; ++nt)
        acc[mt][nt] = __builtin_amdgcn_mfma_f32_16x16x32_bf16(a[mt], b[nt], acc[mt][nt], 0, 0, 0);
  }

  // D[row=(l>>4)*4+r][col=l&15]: m = m0+wm*64+mt*16+l4*4+r, n = n0+wn*64+nt*16+l15
#pragma unroll
  for (int nt = 0; nt < 4; ++nt) {
    const int n = n0 + wn * 64 + nt * 16 + l15;
    const float bv = bias[n];
#pragma unroll
    for (int mt = 0; mt < 4; ++mt) {
#pragma unroll
      for (int r = 0; r < 4; ++r) {
        int m = m0 + wm * 64 + mt * 16 + l4 * 4 + r;
        int b = m / TT, tt = m - b * TT;
        Ct[((size_t)tt * G3_ + n) * 128 + b] = acc[mt][nt][r] + bv;
      }
    }
  }
}

// ---------------- persistent recurrence (r10 best-known): fp16 dot2, 4 batch-groups of 32 b ----------------
// 512 blocks: grp = bid&3 (batches [grp*32,+32)), wb = bid>>2 (4 units). 2 blocks/CU, 8 waves/CU.
__global__ __launch_bounds__(256, 2) void k_recur(
    const float* __restrict__ G1t, const float* __restrict__ GWt,
    const float* __restrict__ W_hh1, const float* __restrict__ W_ih2, const float* __restrict__ W_hh2,
    const float* __restrict__ b_hh1, const float* __restrict__ b_hh2,
    const float* __restrict__ b_ih1, const float* __restrict__ b_ih2,
    float* h1x, float* h1y, float* h2x, float* h2y,
    h2v* hp1x, h2v* hp1y, h2v* hp2x, h2v* hp2y,
    float* __restrict__ h2seqT, unsigned* bars) {
  __shared__ h2v Wl[36 * WP];       // fp16 pairs; rows: mat*12 + g*4 + wid
  __shared__ float S1[4][32];       // h1_new exchange (u-wave -> pair-pack)
  __shared__ float S2[4][32];       // h2_new exchange

  const int tid = threadIdx.x;
  const int bid = blockIdx.x;
  const int grp = bid & 3;
  const int wb  = bid >> 2;
  const int u0 = wb * 4;
  const int bbase = grp * 32;
  const int wid = tid >> 6;          // wave owns unit u0+wid
  const int lane = tid & 63;
  const int kq = lane >> 3;          // k-slice 0..7 (reduced over)
  const int cc = lane & 7;
  const int ugl = u0 + wid;
  const int gb = bbase + cc * 4;
  const int myb = gb + (kq & 3);     // keeper lane (kq<4) owns this b

  // ---- pin fp16 weights in LDS (once) ----
  for (int idx = tid; idx < 36 * 128; idx += 256) {
    int row = idx >> 7; int c4 = (idx & 127) << 2;
    int mm = row / 12, rem = row - mm * 12; int g = rem >> 2, ur = rem & 3;
    int grow = g * HID_ + u0 + ur;
    const float* src = (mm == 0) ? (W_hh1 + (size_t)grow * HID_ + c4)
                     : (mm == 1) ? (W_ih2 + (size_t)grow * EMB_ + c4)
                                 : (W_hh2 + (size_t)grow * HID_ + c4);
    f4x w4 = *reinterpret_cast<const f4x*>(src);
    h2v p0; p0[0] = (_Float16)w4[0]; p0[1] = (_Float16)w4[1];
    h2v p1; p1[0] = (_Float16)w4[2]; p1[1] = (_Float16)w4[3];
    Wl[row * WP + (c4 >> 1)] = p0;
    Wl[row * WP + (c4 >> 1) + 1] = p1;
  }
  const float bh1r = b_hh1[ugl], bh1z = b_hh1[HID_ + ugl], bh1n = b_hh1[2 * HID_ + ugl];
  const float bh2r = b_hh2[ugl], bh2z = b_hh2[HID_ + ugl], bh2n = b_hh2[2 * HID_ + ugl];
  const float bi1r = b_ih1[ugl], bi1z = b_ih1[HID_ + ugl], bi1n = b_ih1[2 * HID_ + ugl];
  const float bi2r = b_ih2[ugl], bi2z = b_ih2[HID_ + ugl], bi2n = b_ih2[2 * HID_ + ugl];
  __syncthreads();

  // ---- prologue: h1[1] = GRU1(h1=0, x0): gh1 = bias only; produce f32 state + fp16 pairs ----
  {
    float h1v = 0.f;
    if (kq < 4) {
      float gr = G1t[(size_t)ugl * 128 + myb];
      float gz = G1t[(size_t)(HID_ + ugl) * 128 + myb];
      float gn = G1t[(size_t)(2 * HID_ + ugl) * 128 + myb];
      float r = sigmoidf_(gr + bh1r);
      float z = sigmoidf_(gz + bh1z);
      float n = tanhf(gn + r * bh1n);
      h1v = (1.f - z) * n;
      h1x[(size_t)ugl * 128 + myb] = h1v;
      S1[wid][cc * 4 + kq] = h1v;
    }
    __syncthreads();
    if (tid < 64) {
      int pi = tid >> 5, b = tid & 31;
      h2v pr; pr[0] = (_Float16)S1[2 * pi][b]; pr[1] = (_Float16)S1[2 * pi + 1][b];
      hp1x[((size_t)(u0 >> 1) + pi) * 128 + bbase + b] = pr;
    }
  }
  gbar(bars, 1u, grp, wb);

  for (int p = 0; p < T_ALL; ++p) {
    const float* h1cur = (p & 1) ? h1y : h1x;
    float*       h1nxt = (p & 1) ? h1x : h1y;
    const float* h2cur = (p & 1) ? h2y : h2x;
    float*       h2nxt = (p & 1) ? h2x : h2y;
    const h2v* hp1cur = (p & 1) ? hp1y : hp1x;
    h2v*       hp1nxt = (p & 1) ? hp1x : hp1y;
    const h2v* hp2cur = (p & 1) ? hp2y : hp2x;
    h2v*       hp2nxt = (p & 1) ? hp2x : hp2y;

    // gate + prev-state prefetch (independent of matmul loads)
    float a_gr, a_gz, a_gn, b_xr, b_xz, b_xn;
    if (p + 1 < T_ENC) {
      const float* gp = G1t + (size_t)(p + 1) * (G3_ * 128);
      a_gr = gp[(size_t)ugl * 128 + myb];
      a_gz = gp[(size_t)(HID_ + ugl) * 128 + myb];
      a_gn = gp[(size_t)(2 * HID_ + ugl) * 128 + myb];
    } else { a_gr = bi1r; a_gz = bi1z; a_gn = bi1n; }
    if (p < T_ENC) { b_xr = bi2r; b_xz = bi2z; b_xn = bi2n; }
    else {
      const float* gp = GWt + (size_t)(p - T_ENC) * (G3_ * 128);
      b_xr = gp[(size_t)ugl * 128 + myb];
      b_xz = gp[(size_t)(HID_ + ugl) * 128 + myb];
      b_xn = gp[(size_t)(2 * HID_ + ugl) * 128 + myb];
    }
    const float h1p = h1cur[(size_t)ugl * 128 + myb];
    const float h2p = h2cur[(size_t)ugl * 128 + myb];

    float acc[4][3][3];   // [e = b&3][mat][gate]
#pragma unroll
    for (int e = 0; e < 4; ++e)
#pragma unroll
      for (int mm = 0; mm < 3; ++mm)
#pragma unroll
        for (int g = 0; g < 3; ++g) acc[e][mm][g] = 0.f;

    hld A1[4], A2[4], B1[4], B2[4], C1[4], C2[4];

    // chunk = 64 k = 32 pairs; lane's 4 pairs = c*32 + kq*4 + j
#define LOADH(P1, P2, c) do { _Pragma("unroll") for (int j_ = 0; j_ < 4; ++j_) { \
      P1[j_].v8 = *reinterpret_cast<const h8v*>(&hp1cur[((size_t)(c) * 32 + kq * 4 + j_) * 128 + gb]); \
      P2[j_].v8 = *reinterpret_cast<const h8v*>(&hp2cur[((size_t)(c) * 32 + kq * 4 + j_) * 128 + gb]); } } while (0)

#define FMAC(c, P1, P2) do { hld w_[9]; \
      _Pragma("unroll") for (int r_ = 0; r_ < 9; ++r_) { int mm_ = r_ / 3, gg_ = r_ - mm_ * 3; \
        w_[r_].v8 = *reinterpret_cast<const h8v*>(&Wl[(mm_ * 12 + gg_ * 4 + wid) * WP + (c) * 32 + kq * 4]); } \
      _Pragma("unroll") for (int j_ = 0; j_ < 4; ++j_) \
        _Pragma("unroll") for (int e_ = 0; e_ < 4; ++e_) \
          _Pragma("unroll") for (int gg_ = 0; gg_ < 3; ++gg_) { \
            acc[e_][0][gg_] = fdot2_(P1[j_].p[e_], w_[gg_].p[j_],     acc[e_][0][gg_]); \
            acc[e_][1][gg_] = fdot2_(P1[j_].p[e_], w_[3 + gg_].p[j_], acc[e_][1][gg_]); \
            acc[e_][2][gg_] = fdot2_(P2[j_].p[e_], w_[6 + gg_].p[j_], acc[e_][2][gg_]); } } while (0)

    // software pipeline: depth-3 lookahead over 8 chunks, static buffer rotation
    LOADH(A1, A2, 0); LOADH(B1, B2, 1); LOADH(C1, C2, 2);
    FMAC(0, A1, A2); LOADH(A1, A2, 3);
    FMAC(1, B1, B2); LOADH(B1, B2, 4);
    FMAC(2, C1, C2); LOADH(C1, C2, 5);
    FMAC(3, A1, A2); LOADH(A1, A2, 6);
    FMAC(4, B1, B2); LOADH(B1, B2, 7);
    FMAC(5, C1, C2);
    FMAC(6, A1, A2);
    FMAC(7, B1, B2);
#undef LOADH
#undef FMAC

    // butterfly over kq lanes (bits 3,4,5); lane kq==e keeps b = gb+e
    float osel[3][3];
#pragma unroll
    for (int mm = 0; mm < 3; ++mm)
#pragma unroll
      for (int g = 0; g < 3; ++g) osel[mm][g] = 0.f;
#pragma unroll
    for (int e = 0; e < 4; ++e)
#pragma unroll
      for (int mm = 0; mm < 3; ++mm)
#pragma unroll
        for (int g = 0; g < 3; ++g) {
          float s = acc[e][mm][g];
          s += __shfl_xor(s, 8); s += __shfl_xor(s, 16); s += __shfl_xor(s, 32);
          if (kq == e) osel[mm][g] = s;
        }

    float h1v = 0.f, h2vv = 0.f;
    if (kq < 4) {
      // A-combine: h1[p+2]  (t_A = p+1)
      if (p + 1 < T_ALL) {
        float r = sigmoidf_(a_gr + osel[0][0] + bh1r);
        float z = sigmoidf_(a_gz + osel[0][1] + bh1z);
        float n = tanhf(a_gn + r * (osel[0][2] + bh1n));
        h1v = (1.f - z) * n + z * h1p;
        h1nxt[(size_t)ugl * 128 + myb] = h1v;
      }
      // B-combine: h2[p+1]  (t_B = p)
      {
        float r = sigmoidf_(b_xr + osel[1][0] + osel[2][0] + bh2r);
        float z = sigmoidf_(b_xz + osel[1][1] + osel[2][1] + bh2z);
        float n = tanhf(b_xn + osel[1][2] + r * (osel[2][2] + bh2n));
        h2vv = (1.f - z) * n + z * h2p;
        h2nxt[(size_t)ugl * 128 + myb] = h2vv;
        if (p >= T_ENC)
          h2seqT[((size_t)(p - T_ENC) * HID_ + ugl) * 128 + myb] = h2vv;
      }
      S1[wid][cc * 4 + kq] = h1v;
      S2[wid][cc * 4 + kq] = h2vv;
    }
    __syncthreads();
    if (tid < 64) {           // pack h1[p+2] fp16 pairs
      int pi = tid >> 5, b = tid & 31;
      h2v pr; pr[0] = (_Float16)S1[2 * pi][b]; pr[1] = (_Float16)S1[2 * pi + 1][b];
      hp1nxt[((size_t)(u0 >> 1) + pi) * 128 + bbase + b] = pr;
    } else if (tid < 128) {   // pack h2[p+1] fp16 pairs
      int pi = (tid - 64) >> 5, b = tid & 31;
      h2v pr; pr[0] = (_Float16)S2[2 * pi][b]; pr[1] = (_Float16)S2[2 * pi + 1][b];
      hp2nxt[((size_t)(u0 >> 1) + pi) * 128 + bbase + b] = pr;
    }

    if (p + 1 < T_ALL) gbar(bars, 2u + (unsigned)p, grp, wb);
  }
}

// ---------------- pack: h2seqT fp32 [t][u][b] -> h2b bf16 [t][u>>3][b][u&7] (MFMA-B layout) ----------------
__global__ __launch_bounds__(256) void k_pack(const float* __restrict__ h2seqT,
                                              ushort_* __restrict__ h2b) {
  __shared__ ushort_ Ls[128][8];
  const int tid = threadIdx.x;
  const int kg = blockIdx.x;          // 0..63
  const int t  = blockIdx.y;          // 0..26
  const int e  = tid >> 5;            // 0..7 (u & 7)
  const int b4 = tid & 31;            // b-quad
  f4x v = *reinterpret_cast<const f4x*>(&h2seqT[((size_t)t * HID_ + kg * 8 + e) * 128 + b4 * 4]);
#pragma unroll
  for (int j = 0; j < 4; ++j) Ls[b4 * 4 + j][e] = f2bf(v[j]);
  __syncthreads();
  if (tid < 128) {
    *reinterpret_cast<s8v*>(&h2b[(((size_t)t * 64 + kg) * 128 + tid) * 8]) =
        *reinterpret_cast<const s8v*>(&Ls[tid][0]);
  }
}

// ---------------- projection: bf16 MFMA, C[m=v][n=b] = Wb(16x32 A) x h2b(32x16 B) ----------------
__global__ __launch_bounds__(256) void k_proj(const ushort_* __restrict__ Wb,
                                              const ushort_* __restrict__ h2b,
                                              const float* __restrict__ bias,
                                              float* __restrict__ out) {
  __shared__ ushort_ As[128 * 40];
  const int tid = threadIdx.x;
  const int t  = blockIdx.x;
  const int v0 = blockIdx.y * 128;
  const int lane = tid & 63;
  const int l15 = lane & 15, l4 = lane >> 4;
  const int wm = (tid >> 6) & 1, wn = tid >> 7;

  f4x acc[4][4];
#pragma unroll
  for (int i = 0; i < 4; ++i)
#pragma unroll
    for (int j = 0; j < 4; ++j) acc[i][j] = (f4x){0.f, 0.f, 0.f, 0.f};

  const int c0 = tid * 2, c1 = c0 + 1;
  const int sv0 = c0 >> 2, sk0 = c0 & 3;
  const int sv1 = c1 >> 2, sk1 = c1 & 3;
  s8v r0, r1;
  r0 = *reinterpret_cast<const s8v*>(&Wb[(size_t)(v0 + sv0) * HID_ + sk0 * 8]);
  r1 = *reinterpret_cast<const s8v*>(&Wb[(size_t)(v0 + sv1) * HID_ + sk1 * 8]);

  for (int ks = 0; ks < 16; ++ks) {
    __syncthreads();
    *reinterpret_cast<s8v*>(&As[sv0 * 40 + sk0 * 8]) = r0;
    *reinterpret_cast<s8v*>(&As[sv1 * 40 + sk1 * 8]) = r1;
    __syncthreads();
    if (ks < 15) {
      r0 = *reinterpret_cast<const s8v*>(&Wb[(size_t)(v0 + sv0) * HID_ + (ks + 1) * 32 + sk0 * 8]);
      r1 = *reinterpret_cast<const s8v*>(&Wb[(size_t)(v0 + sv1) * HID_ + (ks + 1) * 32 + sk1 * 8]);
    }
    s8v a[4], b[4];
#pragma unroll
    for (int mt = 0; mt < 4; ++mt)
      a[mt] = *reinterpret_cast<const s8v*>(&As[(wm * 64 + mt * 16 + l15) * 40 + l4 * 8]);
#pragma unroll
    for (int nt = 0; nt < 4; ++nt)
      b[nt] = *reinterpret_cast<const s8v*>(
          &h2b[(((size_t)t * 64 + ks * 4 + l4) * 128 + wn * 64 + nt * 16 + l15) * 8]);
#pragma unroll
    for (int mt = 0; mt < 4; ++mt)
#pragma unroll
      for (int nt = 0; nt < 4; ++nt)
        acc[mt][nt] = __builtin_amdgcn_mfma_f32_16x16x32_bf16(a[mt], b[nt], acc[mt][nt], 0, 0, 0);
  }

#pragma unroll
  for (int mt = 0; mt < 4; ++mt) {
    const int vb = v0 + wm * 64 + mt * 16 + l4 * 4;
    float bv[4];
    if (vb + 3 < V_) {
      *reinterpret_cast<f4x*>(bv) = *reinterpret_cast<const f4x*>(&bias[vb]);
    } else {
#pragma unroll
      for (int r = 0; r < 4; ++r) bv[r] = (vb + r < V_) ? bias[vb + r] : 0.f;
    }
#pragma unroll
    for (int nt = 0; nt < 4; ++nt) {
      const int bc = wn * 64 + nt * 16 + l15;
      float* cp = &out[((size_t)bc * T_DEC + t) * V_ + vb];
      if (vb + 3 < V_) {
        f4x o = acc[mt][nt];
        o[0] += bv[0]; o[1] += bv[1]; o[2] += bv[2]; o[3] += bv[3];
        *reinterpret_cast<f4x*>(cp) = o;
      } else {
#pragma unroll
        for (int r = 0; r < 4; ++r) if (vb + r < V_) cp[r] = acc[mt][nt][r] + bv[r];
      }
    }
  }
}

// ---------------- log-softmax over rows of 20000 (in place on d_out), f4x vectorized ----------------
__global__ __launch_bounds__(256) void k_logsoftmax(float* __restrict__ out) {
  float* row = out + (size_t)blockIdx.x * V_;
  const int tid = threadIdx.x;
  float mx = -INFINITY, s = 0.f;
  for (int i = tid * 4; i < V_; i += 1024) {
    f4x x = *reinterpret_cast<const f4x*>(&row[i]);
#pragma unroll
    for (int j = 0; j < 4; ++j) {
      float v = x[j];
      if (v > mx) { s = s * expf(mx - v) + 1.f; mx = v; }
      else        { s += expf(v - mx); }
    }
  }
#pragma unroll
  for (int o = 1; o < 64; o <<= 1) {
    float omx = __shfl_xor(mx, o);
    float os  = __shfl_xor(s, o);
    float M = fmaxf(mx, omx);
    s = s * expf(mx - M) + os * expf(omx - M);
    mx = M;
  }
  __shared__ float smx[4], ss[4];
  int wid = tid >> 6, lane = tid & 63;
  if (lane == 0) { smx[wid] = mx; ss[wid] = s; }
  __syncthreads();
  if (tid == 0) {
    float M = smx[0]; float S = ss[0];
#pragma unroll
    for (int w = 1; w < 4; ++w) {
      float M2 = fmaxf(M, smx[w]);
      S = S * expf(M - M2) + ss[w] * expf(smx[w] - M2);
      M = M2;
    }
    ss[0] = logf(S) + M;
  }
  __syncthreads();
  float lse = ss[0];
  for (int i = tid * 4; i < V_; i += 1024) {
    f4x x = *reinterpret_cast<const f4x*>(&row[i]);
    x[0] -= lse; x[1] -= lse; x[2] -= lse; x[3] -= lse;
    *reinterpret_cast<f4x*>(&row[i]) = x;
  }
}

// ---------------- host launch ----------------
extern "C" void kernel_launch(void* const* d_in, const int* in_sizes, int n_in,
                              void* d_out, int out_size, void* d_ws, size_t ws_size,
                              hipStream_t stream) {
  const float* input = (const float*)d_in[0];
  const int*   target = (const int*)d_in[1];
  const float* W_ih1 = (const float*)d_in[2];
  const float* W_hh1 = (const float*)d_in[3];
  const float* b_ih1 = (const float*)d_in[4];
  const float* b_hh1 = (const float*)d_in[5];
  const float* W_ih2 = (const float*)d_in[6];
  const float* W_hh2 = (const float*)d_in[7];
  const float* b_ih2 = (const float*)d_in[8];
  const float* b_hh2 = (const float*)d_in[9];
  const float* E     = (const float*)d_in[10];
  const float* W_out = (const float*)d_in[11];
  const float* b_out = (const float*)d_in[12];
  float* out = (float*)d_out;

  float* ws = (float*)d_ws;
  float* G1t    = ws; ws += (size_t)T_ENC * G3_ * 128;           // [t][gate_row][b] fp32
  float* GWt    = ws; ws += (size_t)T_DEC * G3_ * 128;           // [t][gate_row][b] fp32
  ushort_* Wb   = (ushort_*)ws; ws += (size_t)20096 * HID_ / 2;  // bf16 W_out (padded rows)
  ushort_* h2b  = (ushort_*)ws; ws += (size_t)T_DEC * 64 * 128 * 8 / 2;  // bf16 [t][u>>3][b][u&7]
  float* h2seqT = ws; ws += (size_t)T_DEC * HID_ * 128;          // fp32 [t][u][b]
  ushort_* inb    = (ushort_*)ws; ws += (size_t)B_ * T_ENC * EMB_ / 2;   // bf16 input rows m=b*40+t
  ushort_* wordsb = (ushort_*)ws; ws += (size_t)B_ * T_DEC * HID_ / 2;   // bf16 words rows m=b*27+t
  ushort_* wih1b  = (ushort_*)ws; ws += (size_t)G3_ * EMB_ / 2;          // bf16 W_ih1
  ushort_* wih2b  = (ushort_*)ws; ws += (size_t)G3_ * EMB_ / 2;          // bf16 W_ih2 (full; cols 512.. used)
  float* h1x = ws; ws += HID_ * 128;
  float* h1y = ws; ws += HID_ * 128;
  // ---- contiguous memset region: h2x (f32 state) + hp2x (fp16 pairs) + bars (4 groups) ----
  float* h2x = ws; ws += HID_ * 128;
  h2v* hp2x = (h2v*)ws; ws += HID_ / 2 * 128;
  unsigned* bars = (unsigned*)ws; ws += 1024;
  // ----
  float* h2y = ws; ws += HID_ * 128;
  h2v* hp1x = (h2v*)ws; ws += HID_ / 2 * 128;
  h2v* hp1y = (h2v*)ws; ws += HID_ / 2 * 128;
  h2v* hp2y = (h2v*)ws; ws += HID_ / 2 * 128;

  hipMemsetAsync(h2x, 0, ((size_t)HID_ * 128 + (size_t)HID_ / 2 * 128) * sizeof(float) + 4096, stream);

  // converts (fp32 -> bf16)
  k_gather<<<B_ * T_DEC, 128, 0, stream>>>(target, E, wordsb);
  k_cvt<<<(B_ * T_ENC * EMB_) / 2048, 256, 0, stream>>>(input, inb);
  k_cvt<<<(G3_ * EMB_) / 2048, 256, 0, stream>>>(W_ih1, wih1b);
  k_cvt<<<(G3_ * EMB_) / 2048, 256, 0, stream>>>(W_ih2, wih2b);
  k_cvt<<<(V_ * HID_) / 2048, 256, 0, stream>>>(W_out, Wb);

  // prework gate GEMMs (bf16 MFMA, transposed scatter store)
  k_mm<<<dim3(12, (B_ * T_ENC) / 128), 256, 0, stream>>>(inb, EMB_, wih1b, EMB_, 0, b_ih1,
                                                         G1t, T_ENC, EMB_);
  k_mm<<<dim3(12, (B_ * T_DEC) / 128), 256, 0, stream>>>(wordsb, HID_, wih2b, EMB_, HID_, b_ih2,
                                                         GWt, T_DEC, HID_);

  k_recur<<<NBLK, 256, 0, stream>>>(G1t, GWt, W_hh1, W_ih2, W_hh2, b_hh1, b_hh2, b_ih1, b_ih2,
                                    h1x, h1y, h2x, h2y, hp1x, hp1y, hp2x, hp2y, h2seqT, bars);
  k_pack<<<dim3(64, T_DEC), 256, 0, stream>>>(h2seqT, h2b);

  k_proj<<<dim3(T_DEC, (V_ + 127) / 128), 256, 0, stream>>>(Wb, h2b, b_out, out);
  k_logsoftmax<<<B_ * T_DEC, 256, 0, stream>>>(out);
}

// Round 13
// 1384.580 us; speedup vs baseline: 3.6577x; 1.5957x over previous
//
#include <hip/hip_runtime.h>
#include <math.h>

typedef float f4x __attribute__((ext_vector_type(4)));
typedef short s8v __attribute__((ext_vector_type(8)));
typedef short s4v __attribute__((ext_vector_type(4)));
typedef _Float16 h2v __attribute__((ext_vector_type(2)));
typedef _Float16 h8v __attribute__((ext_vector_type(8)));
typedef unsigned short ushort_;

#define B_    128
#define T_ENC 40
#define T_DEC 27
#define T_ALL 67
#define HID_  512
#define G3_   1536
#define EMB_  1024
#define V_    20000
#define NBLK  512            // 128 unit-groups x 4 batch-groups(32 b); 32-b slices = full 128B lines
#define WP    260            // LDS weight row pitch in h2v units (256 + 4 pad)

__device__ __forceinline__ float sigmoidf_(float x) { return 1.f / (1.f + expf(-x)); }

__device__ __forceinline__ ushort_ f2bf(float f) {   // RNE fp32 -> bf16
  unsigned u = __float_as_uint(f);
  return (ushort_)((u + 0x7FFFu + ((u >> 16) & 1u)) >> 16);
}

__device__ __forceinline__ float fdot2_(h2v a, h2v b, float c) {
#if __has_builtin(__builtin_amdgcn_fdot2)
  return __builtin_amdgcn_fdot2(a, b, c, false);
#else
  return c + (float)a[0] * (float)b[0] + (float)a[1] * (float)b[1];
#endif
}

union hld { h8v v8; h2v p[4]; };
union cvu { h2v v; unsigned u; };

// ------- per-GROUP barrier, fence-lite protocol -------
// Writers' cross-block stores are device-coherent (sc1 atomic stores); __syncthreads drains vmcnt
// before s_barrier, so data is at the coherence point before the arrive-atomic. Readers need only
// an ACQUIRE (invalidate-only) fence after the poll -- no buffer_wbl2 anywhere in the loop.
__device__ __forceinline__ void gbar(unsigned* bars, unsigned barno, int grp, int wb) {
  __syncthreads();   // drains vmcnt: sc1 stores complete at coherence point
  if (threadIdx.x == 0) {
    unsigned* base = bars + (size_t)grp * 256;   // 1 KB per group
    unsigned* leaf = base + (wb >> 5) * 32;      // 4 leaves, 128 B apart
    unsigned* root = base + 128;
    unsigned* gen  = base + 160;
    if (__hip_atomic_fetch_add(leaf, 1u, __ATOMIC_RELAXED, __HIP_MEMORY_SCOPE_AGENT) == barno * 32u - 1u) {
      if (__hip_atomic_fetch_add(root, 1u, __ATOMIC_RELAXED, __HIP_MEMORY_SCOPE_AGENT) == barno * 4u - 1u) {
        __hip_atomic_store(gen, barno, __ATOMIC_RELAXED, __HIP_MEMORY_SCOPE_AGENT);
      }
    }
    while (__hip_atomic_load(gen, __ATOMIC_RELAXED, __HIP_MEMORY_SCOPE_AGENT) < barno) {
      __builtin_amdgcn_s_sleep(1);
    }
    __builtin_amdgcn_fence(__ATOMIC_ACQUIRE, "agent");  // invalidate-only: fresh plain loads
  }
  __syncthreads();
}

// ---------------- gather decoder word embeddings -> bf16 rows m = b*27+t ----------------
__global__ __launch_bounds__(128) void k_gather(const int* __restrict__ target,
                                                const float* __restrict__ E,
                                                ushort_* __restrict__ wordsb) {
  int m = blockIdx.x;
  int b = m / T_DEC, t = m % T_DEC;
  int idx = target[b * 28 + t];
  f4x v = reinterpret_cast<const f4x*>(E + (size_t)idx * HID_)[threadIdx.x];
  s4v o;
#pragma unroll
  for (int j = 0; j < 4; ++j) o[j] = (short)f2bf(v[j]);
  reinterpret_cast<s4v*>(wordsb + (size_t)m * HID_)[threadIdx.x] = o;
}

// ---------------- generic fp32 -> bf16 convert, 8 elems/thread ----------------
__global__ __launch_bounds__(256) void k_cvt(const float* __restrict__ src, ushort_* __restrict__ dst) {
  size_t i = ((size_t)blockIdx.x * 256 + threadIdx.x) * 8;
  f4x a = *reinterpret_cast<const f4x*>(&src[i]);
  f4x b = *reinterpret_cast<const f4x*>(&src[i + 4]);
  s8v o;
#pragma unroll
  for (int j = 0; j < 4; ++j) { o[j] = (short)f2bf(a[j]); o[4 + j] = (short)f2bf(b[j]); }
  *reinterpret_cast<s8v*>(&dst[i]) = o;
}

// ---------------- bf16 MFMA GEMM, transposed scatter-store: Ct[(t*1536+n)*128 + b], m = b*TT+t ----
__global__ __launch_bounds__(256) void k_mm(const ushort_* __restrict__ A, int lda,
                                            const ushort_* __restrict__ Bm, int ldb, int boff,
                                            const float* __restrict__ bias,
                                            float* __restrict__ Ct, int TT, int K) {
  const int tid = threadIdx.x;
  const int lane = tid & 63;
  const int l15 = lane & 15, l4 = lane >> 4;
  const int wm = (tid >> 6) & 1, wn = tid >> 7;
  const int m0 = blockIdx.y * 128;
  const int n0 = blockIdx.x * 128;

  f4x acc[4][4];
#pragma unroll
  for (int i = 0; i < 4; ++i)
#pragma unroll
    for (int j = 0; j < 4; ++j) acc[i][j] = (f4x){0.f, 0.f, 0.f, 0.f};

  for (int ks = 0; ks < K; ks += 32) {
    s8v a[4], b[4];
#pragma unroll
    for (int mt = 0; mt < 4; ++mt)
      a[mt] = *reinterpret_cast<const s8v*>(
          &A[(size_t)(m0 + wm * 64 + mt * 16 + l15) * lda + ks + l4 * 8]);
#pragma unroll
    for (int nt = 0; nt < 4; ++nt)
      b[nt] = *reinterpret_cast<const s8v*>(
          &Bm[(size_t)(n0 + wn * 64 + nt * 16 + l15) * ldb + boff + ks + l4 * 8]);
#pragma unroll
    for (int mt = 0; mt < 4; ++mt)
#pragma unroll
      for (int nt = 0; nt < 4; ++nt)
        acc[mt][nt] = __builtin_amdgcn_mfma_f32_16x16x32_bf16(a[mt], b[nt], acc[mt][nt], 0, 0, 0);
  }

#pragma unroll
  for (int nt = 0; nt < 4; ++nt) {
    const int n = n0 + wn * 64 + nt * 16 + l15;
    const float bv = bias[n];
#pragma unroll
    for (int mt = 0; mt < 4; ++mt) {
#pragma unroll
      for (int r = 0; r < 4; ++r) {
        int m = m0 + wm * 64 + mt * 16 + l4 * 4 + r;
        int b = m / TT, tt = m - b * TT;
        Ct[((size_t)tt * G3_ + n) * 128 + b] = acc[mt][nt][r] + bv;
      }
    }
  }
}

// ---------------- persistent recurrence: register-carried state, fence-lite barrier ----------------
// 512 blocks: grp = bid&3 (batches [grp*32,+32)), wb = bid>>2 (4 units). 2 blocks/CU, 8 waves/CU.
// h circulates ONLY as packed-fp16 [k/2][b] (device-coherent stores); per-lane f32 state in registers.
__global__ __launch_bounds__(256, 2) void k_recur(
    const float* __restrict__ G1t, const float* __restrict__ GWt,
    const float* __restrict__ W_hh1, const float* __restrict__ W_ih2, const float* __restrict__ W_hh2,
    const float* __restrict__ b_hh1, const float* __restrict__ b_hh2,
    const float* __restrict__ b_ih1, const float* __restrict__ b_ih2,
    h2v* hp1x, h2v* hp1y, h2v* hp2x, h2v* hp2y,
    float* __restrict__ h2seqT, unsigned* bars) {
  __shared__ h2v Wl[36 * WP];       // fp16 pairs; rows: mat*12 + g*4 + wid
  __shared__ float S1[4][32];       // h1_new exchange (u-wave -> pair-pack)
  __shared__ float S2[4][32];       // h2_new exchange

  const int tid = threadIdx.x;
  const int bid = blockIdx.x;
  const int grp = bid & 3;
  const int wb  = bid >> 2;
  const int u0 = wb * 4;
  const int bbase = grp * 32;
  const int wid = tid >> 6;          // wave owns unit u0+wid
  const int lane = tid & 63;
  const int kq = lane >> 3;          // k-slice 0..7 (reduced over)
  const int cc = lane & 7;
  const int ugl = u0 + wid;
  const int gb = bbase + cc * 4;
  const int myb = gb + (kq & 3);     // keeper lane (kq<4) owns this b

  // ---- pin fp16 weights in LDS (once) ----
  for (int idx = tid; idx < 36 * 128; idx += 256) {
    int row = idx >> 7; int c4 = (idx & 127) << 2;
    int mm = row / 12, rem = row - mm * 12; int g = rem >> 2, ur = rem & 3;
    int grow = g * HID_ + u0 + ur;
    const float* src = (mm == 0) ? (W_hh1 + (size_t)grow * HID_ + c4)
                     : (mm == 1) ? (W_ih2 + (size_t)grow * EMB_ + c4)
                                 : (W_hh2 + (size_t)grow * HID_ + c4);
    f4x w4 = *reinterpret_cast<const f4x*>(src);
    h2v p0; p0[0] = (_Float16)w4[0]; p0[1] = (_Float16)w4[1];
    h2v p1; p1[0] = (_Float16)w4[2]; p1[1] = (_Float16)w4[3];
    Wl[row * WP + (c4 >> 1)] = p0;
    Wl[row * WP + (c4 >> 1) + 1] = p1;
  }
  const float bh1r = b_hh1[ugl], bh1z = b_hh1[HID_ + ugl], bh1n = b_hh1[2 * HID_ + ugl];
  const float bh2r = b_hh2[ugl], bh2z = b_hh2[HID_ + ugl], bh2n = b_hh2[2 * HID_ + ugl];
  const float bi1r = b_ih1[ugl], bi1z = b_ih1[HID_ + ugl], bi1n = b_ih1[2 * HID_ + ugl];
  const float bi2r = b_ih2[ugl], bi2z = b_ih2[HID_ + ugl], bi2n = b_ih2[2 * HID_ + ugl];
  __syncthreads();

  float h1reg = 0.f, h2reg = 0.f;    // keeper-lane state (replaces f32 global state arrays)

  // ---- prologue: h1[1] = GRU1(h1=0, x0): gh1 = bias only ----
  {
    if (kq < 4) {
      float gr = G1t[(size_t)ugl * 128 + myb];
      float gz = G1t[(size_t)(HID_ + ugl) * 128 + myb];
      float gn = G1t[(size_t)(2 * HID_ + ugl) * 128 + myb];
      float r = sigmoidf_(gr + bh1r);
      float z = sigmoidf_(gz + bh1z);
      float n = tanhf(gn + r * bh1n);
      h1reg = (1.f - z) * n;
      S1[wid][cc * 4 + kq] = h1reg;
    }
    __syncthreads();
    if (tid < 64) {
      int pi = tid >> 5, b = tid & 31;
      h2v pr; pr[0] = (_Float16)S1[2 * pi][b]; pr[1] = (_Float16)S1[2 * pi + 1][b];
      cvu cv; cv.v = pr;
      __hip_atomic_store((unsigned*)&hp1x[((size_t)(u0 >> 1) + pi) * 128 + bbase + b], cv.u,
                         __ATOMIC_RELAXED, __HIP_MEMORY_SCOPE_AGENT);
    }
  }
  gbar(bars, 1u, grp, wb);

  for (int p = 0; p < T_ALL; ++p) {
    const h2v* hp1cur = (p & 1) ? hp1y : hp1x;
    h2v*       hp1nxt = (p & 1) ? hp1x : hp1y;
    const h2v* hp2cur = (p & 1) ? hp2y : hp2x;
    h2v*       hp2nxt = (p & 1) ? hp2x : hp2y;

    // gate prefetch (keeper lanes use; addresses valid for all)
    float a_gr, a_gz, a_gn, b_xr, b_xz, b_xn;
    if (p + 1 < T_ENC) {
      const float* gp = G1t + (size_t)(p + 1) * (G3_ * 128);
      a_gr = gp[(size_t)ugl * 128 + myb];
      a_gz = gp[(size_t)(HID_ + ugl) * 128 + myb];
      a_gn = gp[(size_t)(2 * HID_ + ugl) * 128 + myb];
    } else { a_gr = bi1r; a_gz = bi1z; a_gn = bi1n; }
    if (p < T_ENC) { b_xr = bi2r; b_xz = bi2z; b_xn = bi2n; }
    else {
      const float* gp = GWt + (size_t)(p - T_ENC) * (G3_ * 128);
      b_xr = gp[(size_t)ugl * 128 + myb];
      b_xz = gp[(size_t)(HID_ + ugl) * 128 + myb];
      b_xn = gp[(size_t)(2 * HID_ + ugl) * 128 + myb];
    }

    float acc[4][3][3];   // [e = b&3][mat][gate]
#pragma unroll
    for (int e = 0; e < 4; ++e)
#pragma unroll
      for (int mm = 0; mm < 3; ++mm)
#pragma unroll
        for (int g = 0; g < 3; ++g) acc[e][mm][g] = 0.f;

    hld A1[4], A2[4], B1[4], B2[4], C1[4], C2[4];

    // chunk = 64 k = 32 pairs; lane's 4 pairs = c*32 + kq*4 + j
#define LOADH(P1, P2, c) do { _Pragma("unroll") for (int j_ = 0; j_ < 4; ++j_) { \
      P1[j_].v8 = *reinterpret_cast<const h8v*>(&hp1cur[((size_t)(c) * 32 + kq * 4 + j_) * 128 + gb]); \
      P2[j_].v8 = *reinterpret_cast<const h8v*>(&hp2cur[((size_t)(c) * 32 + kq * 4 + j_) * 128 + gb]); } } while (0)

#define FMAC(c, P1, P2) do { hld w_[9]; \
      _Pragma("unroll") for (int r_ = 0; r_ < 9; ++r_) { int mm_ = r_ / 3, gg_ = r_ - mm_ * 3; \
        w_[r_].v8 = *reinterpret_cast<const h8v*>(&Wl[(mm_ * 12 + gg_ * 4 + wid) * WP + (c) * 32 + kq * 4]); } \
      _Pragma("unroll") for (int j_ = 0; j_ < 4; ++j_) \
        _Pragma("unroll") for (int e_ = 0; e_ < 4; ++e_) \
          _Pragma("unroll") for (int gg_ = 0; gg_ < 3; ++gg_) { \
            acc[e_][0][gg_] = fdot2_(P1[j_].p[e_], w_[gg_].p[j_],     acc[e_][0][gg_]); \
            acc[e_][1][gg_] = fdot2_(P1[j_].p[e_], w_[3 + gg_].p[j_], acc[e_][1][gg_]); \
            acc[e_][2][gg_] = fdot2_(P2[j_].p[e_], w_[6 + gg_].p[j_], acc[e_][2][gg_]); } } while (0)

    // software pipeline: depth-3 lookahead over 8 chunks, static buffer rotation
    LOADH(A1, A2, 0); LOADH(B1, B2, 1); LOADH(C1, C2, 2);
    FMAC(0, A1, A2); LOADH(A1, A2, 3);
    FMAC(1, B1, B2); LOADH(B1, B2, 4);
    FMAC(2, C1, C2); LOADH(C1, C2, 5);
    FMAC(3, A1, A2); LOADH(A1, A2, 6);
    FMAC(4, B1, B2); LOADH(B1, B2, 7);
    FMAC(5, C1, C2);
    FMAC(6, A1, A2);
    FMAC(7, B1, B2);
#undef LOADH
#undef FMAC

    // butterfly over kq lanes (bits 3,4,5); lane kq==e keeps b = gb+e
    float osel[3][3];
#pragma unroll
    for (int mm = 0; mm < 3; ++mm)
#pragma unroll
      for (int g = 0; g < 3; ++g) osel[mm][g] = 0.f;
#pragma unroll
    for (int e = 0; e < 4; ++e)
#pragma unroll
      for (int mm = 0; mm < 3; ++mm)
#pragma unroll
        for (int g = 0; g < 3; ++g) {
          float s = acc[e][mm][g];
          s += __shfl_xor(s, 8); s += __shfl_xor(s, 16); s += __shfl_xor(s, 32);
          if (kq == e) osel[mm][g] = s;
        }

    if (kq < 4) {
      float h1new = h1reg, h2new;
      // A-combine: h1[p+2]  (t_A = p+1)
      if (p + 1 < T_ALL) {
        float r = sigmoidf_(a_gr + osel[0][0] + bh1r);
        float z = sigmoidf_(a_gz + osel[0][1] + bh1z);
        float n = tanhf(a_gn + r * (osel[0][2] + bh1n));
        h1new = (1.f - z) * n + z * h1reg;
      }
      // B-combine: h2[p+1]  (t_B = p)
      {
        float r = sigmoidf_(b_xr + osel[1][0] + osel[2][0] + bh2r);
        float z = sigmoidf_(b_xz + osel[1][1] + osel[2][1] + bh2z);
        float n = tanhf(b_xn + osel[1][2] + r * (osel[2][2] + bh2n));
        h2new = (1.f - z) * n + z * h2reg;
        if (p >= T_ENC)
          h2seqT[((size_t)(p - T_ENC) * HID_ + ugl) * 128 + myb] = h2new;   // plain; read post-kernel
      }
      h1reg = h1new; h2reg = h2new;
      S1[wid][cc * 4 + kq] = h1new;
      S2[wid][cc * 4 + kq] = h2new;
    }
    __syncthreads();
    if (tid < 64) {           // pack h1[p+2] fp16 pairs (device-coherent stores)
      int pi = tid >> 5, b = tid & 31;
      h2v pr; pr[0] = (_Float16)S1[2 * pi][b]; pr[1] = (_Float16)S1[2 * pi + 1][b];
      cvu cv; cv.v = pr;
      __hip_atomic_store((unsigned*)&hp1nxt[((size_t)(u0 >> 1) + pi) * 128 + bbase + b], cv.u,
                         __ATOMIC_RELAXED, __HIP_MEMORY_SCOPE_AGENT);
    } else if (tid < 128) {   // pack h2[p+1] fp16 pairs
      int pi = (tid - 64) >> 5, b = tid & 31;
      h2v pr; pr[0] = (_Float16)S2[2 * pi][b]; pr[1] = (_Float16)S2[2 * pi + 1][b];
      cvu cv; cv.v = pr;
      __hip_atomic_store((unsigned*)&hp2nxt[((size_t)(u0 >> 1) + pi) * 128 + bbase + b], cv.u,
                         __ATOMIC_RELAXED, __HIP_MEMORY_SCOPE_AGENT);
    }

    if (p + 1 < T_ALL) gbar(bars, 2u + (unsigned)p, grp, wb);
  }
}

// ---------------- pack: h2seqT fp32 [t][u][b] -> h2b bf16 [t][u>>3][b][u&7] (MFMA-B layout) ----------------
__global__ __launch_bounds__(256) void k_pack(const float* __restrict__ h2seqT,
                                              ushort_* __restrict__ h2b) {
  __shared__ ushort_ Ls[128][8];
  const int tid = threadIdx.x;
  const int kg = blockIdx.x;          // 0..63
  const int t  = blockIdx.y;          // 0..26
  const int e  = tid >> 5;            // 0..7 (u & 7)
  const int b4 = tid & 31;            // b-quad
  f4x v = *reinterpret_cast<const f4x*>(&h2seqT[((size_t)t * HID_ + kg * 8 + e) * 128 + b4 * 4]);
#pragma unroll
  for (int j = 0; j < 4; ++j) Ls[b4 * 4 + j][e] = f2bf(v[j]);
  __syncthreads();
  if (tid < 128) {
    *reinterpret_cast<s8v*>(&h2b[(((size_t)t * 64 + kg) * 128 + tid) * 8]) =
        *reinterpret_cast<const s8v*>(&Ls[tid][0]);
  }
}

// ---------------- projection: bf16 MFMA, C[m=v][n=b] = Wb(16x32 A) x h2b(32x16 B) ----------------
__global__ __launch_bounds__(256) void k_proj(const ushort_* __restrict__ Wb,
                                              const ushort_* __restrict__ h2b,
                                              const float* __restrict__ bias,
                                              float* __restrict__ out) {
  __shared__ ushort_ As[128 * 40];
  const int tid = threadIdx.x;
  const int t  = blockIdx.x;
  const int v0 = blockIdx.y * 128;
  const int lane = tid & 63;
  const int l15 = lane & 15, l4 = lane >> 4;
  const int wm = (tid >> 6) & 1, wn = tid >> 7;

  f4x acc[4][4];
#pragma unroll
  for (int i = 0; i < 4; ++i)
#pragma unroll
    for (int j = 0; j < 4; ++j) acc[i][j] = (f4x){0.f, 0.f, 0.f, 0.f};

  const int c0 = tid * 2, c1 = c0 + 1;
  const int sv0 = c0 >> 2, sk0 = c0 & 3;
  const int sv1 = c1 >> 2, sk1 = c1 & 3;
  s8v r0, r1;
  r0 = *reinterpret_cast<const s8v*>(&Wb[(size_t)(v0 + sv0) * HID_ + sk0 * 8]);
  r1 = *reinterpret_cast<const s8v*>(&Wb[(size_t)(v0 + sv1) * HID_ + sk1 * 8]);

  for (int ks = 0; ks < 16; ++ks) {
    __syncthreads();
    *reinterpret_cast<s8v*>(&As[sv0 * 40 + sk0 * 8]) = r0;
    *reinterpret_cast<s8v*>(&As[sv1 * 40 + sk1 * 8]) = r1;
    __syncthreads();
    if (ks < 15) {
      r0 = *reinterpret_cast<const s8v*>(&Wb[(size_t)(v0 + sv0) * HID_ + (ks + 1) * 32 + sk0 * 8]);
      r1 = *reinterpret_cast<const s8v*>(&Wb[(size_t)(v0 + sv1) * HID_ + (ks + 1) * 32 + sk1 * 8]);
    }
    s8v a[4], b[4];
#pragma unroll
    for (int mt = 0; mt < 4; ++mt)
      a[mt] = *reinterpret_cast<const s8v*>(&As[(wm * 64 + mt * 16 + l15) * 40 + l4 * 8]);
#pragma unroll
    for (int nt = 0; nt < 4; ++nt)
      b[nt] = *reinterpret_cast<const s8v*>(
          &h2b[(((size_t)t * 64 + ks * 4 + l4) * 128 + wn * 64 + nt * 16 + l15) * 8]);
#pragma unroll
    for (int mt = 0; mt < 4; ++mt)
#pragma unroll
      for (int nt = 0; nt < 4; ++nt)
        acc[mt][nt] = __builtin_amdgcn_mfma_f32_16x16x32_bf16(a[mt], b[nt], acc[mt][nt], 0, 0, 0);
  }

#pragma unroll
  for (int mt = 0; mt < 4; ++mt) {
    const int vb = v0 + wm * 64 + mt * 16 + l4 * 4;
    float bv[4];
    if (vb + 3 < V_) {
      *reinterpret_cast<f4x*>(bv) = *reinterpret_cast<const f4x*>(&bias[vb]);
    } else {
#pragma unroll
      for (int r = 0; r < 4; ++r) bv[r] = (vb + r < V_) ? bias[vb + r] : 0.f;
    }
#pragma unroll
    for (int nt = 0; nt < 4; ++nt) {
      const int bc = wn * 64 + nt * 16 + l15;
      float* cp = &out[((size_t)bc * T_DEC + t) * V_ + vb];
      if (vb + 3 < V_) {
        f4x o = acc[mt][nt];
        o[0] += bv[0]; o[1] += bv[1]; o[2] += bv[2]; o[3] += bv[3];
        *reinterpret_cast<f4x*>(cp) = o;
      } else {
#pragma unroll
        for (int r = 0; r < 4; ++r) if (vb + r < V_) cp[r] = acc[mt][nt][r] + bv[r];
      }
    }
  }
}

// ---------------- log-softmax over rows of 20000 (in place on d_out), f4x vectorized ----------------
__global__ __launch_bounds__(256) void k_logsoftmax(float* __restrict__ out) {
  float* row = out + (size_t)blockIdx.x * V_;
  const int tid = threadIdx.x;
  float mx = -INFINITY, s = 0.f;
  for (int i = tid * 4; i < V_; i += 1024) {
    f4x x = *reinterpret_cast<const f4x*>(&row[i]);
#pragma unroll
    for (int j = 0; j < 4; ++j) {
      float v = x[j];
      if (v > mx) { s = s * expf(mx - v) + 1.f; mx = v; }
      else        { s += expf(v - mx); }
    }
  }
#pragma unroll
  for (int o = 1; o < 64; o <<= 1) {
    float omx = __shfl_xor(mx, o);
    float os  = __shfl_xor(s, o);
    float M = fmaxf(mx, omx);
    s = s * expf(mx - M) + os * expf(omx - M);
    mx = M;
  }
  __shared__ float smx[4], ss[4];
  int wid = tid >> 6, lane = tid & 63;
  if (lane == 0) { smx[wid] = mx; ss[wid] = s; }
  __syncthreads();
  if (tid == 0) {
    float M = smx[0]; float S = ss[0];
#pragma unroll
    for (int w = 1; w < 4; ++w) {
      float M2 = fmaxf(M, smx[w]);
      S = S * expf(M - M2) + ss[w] * expf(smx[w] - M2);
      M = M2;
    }
    ss[0] = logf(S) + M;
  }
  __syncthreads();
  float lse = ss[0];
  for (int i = tid * 4; i < V_; i += 1024) {
    f4x x = *reinterpret_cast<const f4x*>(&row[i]);
    x[0] -= lse; x[1] -= lse; x[2] -= lse; x[3] -= lse;
    *reinterpret_cast<f4x*>(&row[i]) = x;
  }
}

// ---------------- host launch ----------------
extern "C" void kernel_launch(void* const* d_in, const int* in_sizes, int n_in,
                              void* d_out, int out_size, void* d_ws, size_t ws_size,
                              hipStream_t stream) {
  const float* input = (const float*)d_in[0];
  const int*   target = (const int*)d_in[1];
  const float* W_ih1 = (const float*)d_in[2];
  const float* W_hh1 = (const float*)d_in[3];
  const float* b_ih1 = (const float*)d_in[4];
  const float* b_hh1 = (const float*)d_in[5];
  const float* W_ih2 = (const float*)d_in[6];
  const float* W_hh2 = (const float*)d_in[7];
  const float* b_ih2 = (const float*)d_in[8];
  const float* b_hh2 = (const float*)d_in[9];
  const float* E     = (const float*)d_in[10];
  const float* W_out = (const float*)d_in[11];
  const float* b_out = (const float*)d_in[12];
  float* out = (float*)d_out;

  float* ws = (float*)d_ws;
  float* G1t    = ws; ws += (size_t)T_ENC * G3_ * 128;           // [t][gate_row][b] fp32
  float* GWt    = ws; ws += (size_t)T_DEC * G3_ * 128;           // [t][gate_row][b] fp32
  ushort_* Wb   = (ushort_*)ws; ws += (size_t)20096 * HID_ / 2;  // bf16 W_out (padded rows)
  ushort_* h2b  = (ushort_*)ws; ws += (size_t)T_DEC * 64 * 128 * 8 / 2;  // bf16 [t][u>>3][b][u&7]
  float* h2seqT = ws; ws += (size_t)T_DEC * HID_ * 128;          // fp32 [t][u][b]
  ushort_* inb    = (ushort_*)ws; ws += (size_t)B_ * T_ENC * EMB_ / 2;   // bf16 input rows m=b*40+t
  ushort_* wordsb = (ushort_*)ws; ws += (size_t)B_ * T_DEC * HID_ / 2;   // bf16 words rows m=b*27+t
  ushort_* wih1b  = (ushort_*)ws; ws += (size_t)G3_ * EMB_ / 2;          // bf16 W_ih1
  ushort_* wih2b  = (ushort_*)ws; ws += (size_t)G3_ * EMB_ / 2;          // bf16 W_ih2
  // ---- contiguous memset region: hp2x (fp16 pairs) + bars (4 groups) ----
  h2v* hp2x = (h2v*)ws; ws += HID_ / 2 * 128;
  unsigned* bars = (unsigned*)ws; ws += 1024;
  // ----
  h2v* hp1x = (h2v*)ws; ws += HID_ / 2 * 128;
  h2v* hp1y = (h2v*)ws; ws += HID_ / 2 * 128;
  h2v* hp2y = (h2v*)ws; ws += HID_ / 2 * 128;

  hipMemsetAsync(hp2x, 0, (size_t)HID_ / 2 * 128 * sizeof(h2v) + 4096, stream);

  // converts (fp32 -> bf16)
  k_gather<<<B_ * T_DEC, 128, 0, stream>>>(target, E, wordsb);
  k_cvt<<<(B_ * T_ENC * EMB_) / 2048, 256, 0, stream>>>(input, inb);
  k_cvt<<<(G3_ * EMB_) / 2048, 256, 0, stream>>>(W_ih1, wih1b);
  k_cvt<<<(G3_ * EMB_) / 2048, 256, 0, stream>>>(W_ih2, wih2b);
  k_cvt<<<(V_ * HID_) / 2048, 256, 0, stream>>>(W_out, Wb);

  // prework gate GEMMs (bf16 MFMA, transposed scatter store)
  k_mm<<<dim3(12, (B_ * T_ENC) / 128), 256, 0, stream>>>(inb, EMB_, wih1b, EMB_, 0, b_ih1,
                                                         G1t, T_ENC, EMB_);
  k_mm<<<dim3(12, (B_ * T_DEC) / 128), 256, 0, stream>>>(wordsb, HID_, wih2b, EMB_, HID_, b_ih2,
                                                         GWt, T_DEC, HID_);

  k_recur<<<NBLK, 256, 0, stream>>>(G1t, GWt, W_hh1, W_ih2, W_hh2, b_hh1, b_hh2, b_ih1, b_ih2,
                                    hp1x, hp1y, hp2x, hp2y, h2seqT, bars);
  k_pack<<<dim3(64, T_DEC), 256, 0, stream>>>(h2seqT, h2b);

  k_proj<<<dim3(T_DEC, (V_ + 127) / 128), 256, 0, stream>>>(Wb, h2b, b_out, out);
  k_logsoftmax<<<B_ * T_DEC, 256, 0, stream>>>(out);
}

// Round 14
// 1106.587 us; speedup vs baseline: 4.5766x; 1.2512x over previous
//
#include <hip/hip_runtime.h>
#include <math.h>

typedef float f4x __attribute__((ext_vector_type(4)));
typedef short s8v __attribute__((ext_vector_type(8)));
typedef short s4v __attribute__((ext_vector_type(4)));
typedef unsigned short ushort_;

#define B_    128
#define T_ENC 40
#define T_DEC 27
#define T_ALL 67
#define HID_  512
#define G3_   1536
#define EMB_  1024
#define V_    20000
#define NBLK  512            // 128 unit-groups(4u) x 4 batch-groups(32 b)
#define WLP   520            // Wl row pitch in shorts (512 + 8 pad)

__device__ __forceinline__ float sigmoidf_(float x) { return 1.f / (1.f + expf(-x)); }

__device__ __forceinline__ ushort_ f2bf(float f) {   // RNE fp32 -> bf16
  unsigned u = __float_as_uint(f);
  return (ushort_)((u + 0x7FFFu + ((u >> 16) & 1u)) >> 16);
}

// ------- per-GROUP barrier, fence-lite protocol (r13, validated) -------
__device__ __forceinline__ void gbar(unsigned* bars, unsigned barno, int grp, int wb) {
  __syncthreads();   // drains vmcnt: coherent stores complete before arrive
  if (threadIdx.x == 0) {
    unsigned* base = bars + (size_t)grp * 256;
    unsigned* leaf = base + (wb >> 5) * 32;
    unsigned* root = base + 128;
    unsigned* gen  = base + 160;
    if (__hip_atomic_fetch_add(leaf, 1u, __ATOMIC_RELAXED, __HIP_MEMORY_SCOPE_AGENT) == barno * 32u - 1u) {
      if (__hip_atomic_fetch_add(root, 1u, __ATOMIC_RELAXED, __HIP_MEMORY_SCOPE_AGENT) == barno * 4u - 1u) {
        __hip_atomic_store(gen, barno, __ATOMIC_RELAXED, __HIP_MEMORY_SCOPE_AGENT);
      }
    }
    while (__hip_atomic_load(gen, __ATOMIC_RELAXED, __HIP_MEMORY_SCOPE_AGENT) < barno) {
      __builtin_amdgcn_s_sleep(1);
    }
    __builtin_amdgcn_fence(__ATOMIC_ACQUIRE, "agent");  // invalidate-only
  }
  __syncthreads();
}

// ---------------- gather decoder word embeddings -> bf16 rows m = b*27+t ----------------
__global__ __launch_bounds__(128) void k_gather(const int* __restrict__ target,
                                                const float* __restrict__ E,
                                                ushort_* __restrict__ wordsb) {
  int m = blockIdx.x;
  int b = m / T_DEC, t = m % T_DEC;
  int idx = target[b * 28 + t];
  f4x v = reinterpret_cast<const f4x*>(E + (size_t)idx * HID_)[threadIdx.x];
  s4v o;
#pragma unroll
  for (int j = 0; j < 4; ++j) o[j] = (short)f2bf(v[j]);
  reinterpret_cast<s4v*>(wordsb + (size_t)m * HID_)[threadIdx.x] = o;
}

// ---------------- generic fp32 -> bf16 convert, 8 elems/thread ----------------
__global__ __launch_bounds__(256) void k_cvt(const float* __restrict__ src, ushort_* __restrict__ dst) {
  size_t i = ((size_t)blockIdx.x * 256 + threadIdx.x) * 8;
  f4x a = *reinterpret_cast<const f4x*>(&src[i]);
  f4x b = *reinterpret_cast<const f4x*>(&src[i + 4]);
  s8v o;
#pragma unroll
  for (int j = 0; j < 4; ++j) { o[j] = (short)f2bf(a[j]); o[4 + j] = (short)f2bf(b[j]); }
  *reinterpret_cast<s8v*>(&dst[i]) = o;
}

// ---------------- bf16 MFMA GEMM, transposed scatter-store: Ct[(t*1536+n)*128 + b], m = b*TT+t ----
__global__ __launch_bounds__(256) void k_mm(const ushort_* __restrict__ A, int lda,
                                            const ushort_* __restrict__ Bm, int ldb, int boff,
                                            const float* __restrict__ bias,
                                            float* __restrict__ Ct, int TT, int K) {
  const int tid = threadIdx.x;
  const int lane = tid & 63;
  const int l15 = lane & 15, l4 = lane >> 4;
  const int wm = (tid >> 6) & 1, wn = tid >> 7;
  const int m0 = blockIdx.y * 128;
  const int n0 = blockIdx.x * 128;

  f4x acc[4][4];
#pragma unroll
  for (int i = 0; i < 4; ++i)
#pragma unroll
    for (int j = 0; j < 4; ++j) acc[i][j] = (f4x){0.f, 0.f, 0.f, 0.f};

  for (int ks = 0; ks < K; ks += 32) {
    s8v a[4], b[4];
#pragma unroll
    for (int mt = 0; mt < 4; ++mt)
      a[mt] = *reinterpret_cast<const s8v*>(
          &A[(size_t)(m0 + wm * 64 + mt * 16 + l15) * lda + ks + l4 * 8]);
#pragma unroll
    for (int nt = 0; nt < 4; ++nt)
      b[nt] = *reinterpret_cast<const s8v*>(
          &Bm[(size_t)(n0 + wn * 64 + nt * 16 + l15) * ldb + boff + ks + l4 * 8]);
#pragma unroll
    for (int mt = 0; mt < 4; ++mt)
#pragma unroll
      for (int nt = 0; nt < 4; ++nt)
        acc[mt][nt] = __builtin_amdgcn_mfma_f32_16x16x32_bf16(a[mt], b[nt], acc[mt][nt], 0, 0, 0);
  }

#pragma unroll
  for (int nt = 0; nt < 4; ++nt) {
    const int n = n0 + wn * 64 + nt * 16 + l15;
    const float bv = bias[n];
#pragma unroll
    for (int mt = 0; mt < 4; ++mt) {
#pragma unroll
      for (int r = 0; r < 4; ++r) {
        int m = m0 + wm * 64 + mt * 16 + l4 * 4 + r;
        int b = m / TT, tt = m - b * TT;
        Ct[((size_t)tt * G3_ + n) * 128 + b] = acc[mt][nt][r] + bv;
      }
    }
  }
}

// ---------------- persistent recurrence: MFMA gate matmuls, register state, fence-lite barrier ----
// 512 blocks: grp = bid&3 (batches [grp*32,+32)), wb = bid>>2 (4 units).
// h circulates as bf16 [k>>3][b][k&7] (MFMA-B layout, coherent 8B atomic pack stores).
// Waves 0,1: 2 MFMA jobs each; waves 2,3: 1 job + combine (register state) + pack.
__global__ __launch_bounds__(256, 2) void k_recur(
    const float* __restrict__ G1t, const float* __restrict__ GWt,
    const float* __restrict__ W_hh1, const float* __restrict__ W_ih2, const float* __restrict__ W_hh2,
    const float* __restrict__ b_hh1, const float* __restrict__ b_hh2,
    const float* __restrict__ b_ih1, const float* __restrict__ b_ih2,
    ushort_* hp1x, ushort_* hp1y, ushort_* hp2x, ushort_* hp2y,
    float* __restrict__ h2seqT, unsigned* bars) {
  __shared__ ushort_ Wl[48 * WLP];   // bf16 A-tiles: [mat*16 + gate*4 + unit][k], pad rows 12..15 zero
  __shared__ float Scr[36 * 32];     // C exchange: [(mat*3+gate)*4+unit][b32]
  __shared__ float S1[4][32];        // h1_new exchange -> pack
  __shared__ float S2[4][32];        // h2_new exchange

  const int tid = threadIdx.x;
  const int bid = blockIdx.x;
  const int grp = bid & 3;
  const int wb  = bid >> 2;
  const int u0 = wb * 4;
  const int bbase = grp * 32;
  const int wid = tid >> 6;
  const int lane = tid & 63;
  const int l15 = lane & 15, l4 = lane >> 4;
  const int kg = u0 >> 3;            // hp k-octet owned by this block
  const int e0 = u0 & 7;             // element offset within octet (0 or 4)
  // combiner mapping (waves 2,3): tc = tid-128: u = tc>>5, b32 = tc&31
  const int tc = tid & 127;
  const int cu = tc >> 5, cb = tc & 31;
  const int ugl = u0 + cu;
  const int myb = bbase + cb;

  // ---- zero then fill bf16 weight tiles in LDS (once) ----
  for (int i = tid; i < 48 * WLP / 8; i += 256)
    reinterpret_cast<s8v*>(Wl)[i] = (s8v){0, 0, 0, 0, 0, 0, 0, 0};
  __syncthreads();
  for (int idx = tid; idx < 36 * 128; idx += 256) {
    int row = idx >> 7; int c4 = (idx & 127) << 2;
    int mm = row / 12, rem = row - mm * 12; int g = rem >> 2, ur = rem & 3;
    int grow = g * HID_ + u0 + ur;
    const float* src = (mm == 0) ? (W_hh1 + (size_t)grow * HID_ + c4)
                     : (mm == 1) ? (W_ih2 + (size_t)grow * EMB_ + c4)
                                 : (W_hh2 + (size_t)grow * HID_ + c4);
    f4x w4 = *reinterpret_cast<const f4x*>(src);
    s4v o;
#pragma unroll
    for (int j = 0; j < 4; ++j) o[j] = (short)f2bf(w4[j]);
    *reinterpret_cast<s4v*>(&Wl[(mm * 16 + rem) * WLP + c4]) = o;
  }
  const float bh1r = b_hh1[ugl], bh1z = b_hh1[HID_ + ugl], bh1n = b_hh1[2 * HID_ + ugl];
  const float bh2r = b_hh2[ugl], bh2z = b_hh2[HID_ + ugl], bh2n = b_hh2[2 * HID_ + ugl];
  const float bi1r = b_ih1[ugl], bi1z = b_ih1[HID_ + ugl], bi1n = b_ih1[2 * HID_ + ugl];
  const float bi2r = b_ih2[ugl], bi2z = b_ih2[HID_ + ugl], bi2n = b_ih2[2 * HID_ + ugl];
  __syncthreads();

  float h1reg = 0.f, h2reg = 0.f;    // combiner-thread state (waves 2,3)

  // ---- prologue: h1[1] = GRU1(h1=0, x0): gh1 = bias only ----
  if (tid >= 128) {
    float gr = G1t[(size_t)ugl * 128 + myb];
    float gz = G1t[(size_t)(HID_ + ugl) * 128 + myb];
    float gn = G1t[(size_t)(2 * HID_ + ugl) * 128 + myb];
    float r = sigmoidf_(gr + bh1r);
    float z = sigmoidf_(gz + bh1z);
    float n = tanhf(gn + r * bh1n);
    h1reg = (1.f - z) * n;
    S1[cu][cb] = h1reg;
  }
  __syncthreads();
  if (tid >= 128 && tid < 160) {
    int b = tid - 128;
    unsigned long long v = (unsigned long long)f2bf(S1[0][b])
        | ((unsigned long long)f2bf(S1[1][b]) << 16)
        | ((unsigned long long)f2bf(S1[2][b]) << 32)
        | ((unsigned long long)f2bf(S1[3][b]) << 48);
    __hip_atomic_store(reinterpret_cast<unsigned long long*>(
        &hp1x[((size_t)kg * 128 + bbase + b) * 8 + e0]), v,
        __ATOMIC_RELAXED, __HIP_MEMORY_SCOPE_AGENT);
  }
  gbar(bars, 1u, grp, wb);

  for (int p = 0; p < T_ALL; ++p) {
    const ushort_* hp1cur = (p & 1) ? hp1y : hp1x;
    ushort_*       hp1nxt = (p & 1) ? hp1x : hp1y;
    const ushort_* hp2cur = (p & 1) ? hp2y : hp2x;
    ushort_*       hp2nxt = (p & 1) ? hp2x : hp2y;

    // gate prefetch (combiner waves only; overlaps with MFMA jobs)
    float a_gr = bi1r, a_gz = bi1z, a_gn = bi1n;
    float b_xr = bi2r, b_xz = bi2z, b_xn = bi2n;
    if (tid >= 128) {
      if (p + 1 < T_ENC) {
        const float* gp = G1t + (size_t)(p + 1) * (G3_ * 128);
        a_gr = gp[(size_t)ugl * 128 + myb];
        a_gz = gp[(size_t)(HID_ + ugl) * 128 + myb];
        a_gn = gp[(size_t)(2 * HID_ + ugl) * 128 + myb];
      }
      if (p >= T_ENC) {
        const float* gp = GWt + (size_t)(p - T_ENC) * (G3_ * 128);
        b_xr = gp[(size_t)ugl * 128 + myb];
        b_xz = gp[(size_t)(HID_ + ugl) * 128 + myb];
        b_xn = gp[(size_t)(2 * HID_ + ugl) * 128 + myb];
      }
    }

    // ---- MFMA jobs: job(mat, nt): C[16x16] over K=512 ----
#define RUN_JOB(MAT, NT, HP) do { \
      f4x c_ = (f4x){0.f, 0.f, 0.f, 0.f}; \
      const int arow_ = ((MAT) * 16 + l15) * WLP + l4 * 8; \
      const size_t boff_ = ((size_t)l4 * 128 + bbase + (NT) * 16 + l15) * 8; \
      _Pragma("unroll") \
      for (int ks_ = 0; ks_ < 16; ++ks_) { \
        s8v a_ = *reinterpret_cast<const s8v*>(&Wl[arow_ + ks_ * 32]); \
        s8v b_ = *reinterpret_cast<const s8v*>(&(HP)[boff_ + (size_t)ks_ * 4096]); \
        c_ = __builtin_amdgcn_mfma_f32_16x16x32_bf16(a_, b_, c_, 0, 0, 0); \
      } \
      if (l4 < 3) { \
        _Pragma("unroll") \
        for (int r_ = 0; r_ < 4; ++r_) \
          Scr[(((MAT) * 3 + l4) * 4 + r_) * 32 + (NT) * 16 + l15] = c_[r_]; \
      } } while (0)

    if (wid == 0)      { RUN_JOB(0, 0, hp1cur); RUN_JOB(0, 1, hp1cur); }
    else if (wid == 1) { RUN_JOB(1, 0, hp1cur); RUN_JOB(1, 1, hp1cur); }
    else if (wid == 2) { RUN_JOB(2, 0, hp2cur); }
    else               { RUN_JOB(2, 1, hp2cur); }
#undef RUN_JOB
    __syncthreads();

    // ---- combine (waves 2,3): og[mat][gate] from Scr ----
    if (tid >= 128) {
      float og[3][3];
#pragma unroll
      for (int mm = 0; mm < 3; ++mm)
#pragma unroll
        for (int g = 0; g < 3; ++g)
          og[mm][g] = Scr[((mm * 3 + g) * 4 + cu) * 32 + cb];

      float h1new = h1reg, h2new;
      if (p + 1 < T_ALL) {   // A-combine: h1[p+2]
        float r = sigmoidf_(a_gr + og[0][0] + bh1r);
        float z = sigmoidf_(a_gz + og[0][1] + bh1z);
        float n = tanhf(a_gn + r * (og[0][2] + bh1n));
        h1new = (1.f - z) * n + z * h1reg;
      }
      {                      // B-combine: h2[p+1]
        float r = sigmoidf_(b_xr + og[1][0] + og[2][0] + bh2r);
        float z = sigmoidf_(b_xz + og[1][1] + og[2][1] + bh2z);
        float n = tanhf(b_xn + og[1][2] + r * (og[2][2] + bh2n));
        h2new = (1.f - z) * n + z * h2reg;
        if (p >= T_ENC)
          h2seqT[((size_t)(p - T_ENC) * HID_ + ugl) * 128 + myb] = h2new;
      }
      h1reg = h1new; h2reg = h2new;
      S1[cu][cb] = h1new;
      S2[cu][cb] = h2new;
    }
    __syncthreads();

    // ---- pack (waves 2,3 low threads): 8B coherent stores into MFMA-B layout ----
    if (tid >= 128 && tid < 160) {
      int b = tid - 128;
      unsigned long long v = (unsigned long long)f2bf(S1[0][b])
          | ((unsigned long long)f2bf(S1[1][b]) << 16)
          | ((unsigned long long)f2bf(S1[2][b]) << 32)
          | ((unsigned long long)f2bf(S1[3][b]) << 48);
      __hip_atomic_store(reinterpret_cast<unsigned long long*>(
          &hp1nxt[((size_t)kg * 128 + bbase + b) * 8 + e0]), v,
          __ATOMIC_RELAXED, __HIP_MEMORY_SCOPE_AGENT);
    } else if (tid >= 160 && tid < 192) {
      int b = tid - 160;
      unsigned long long v = (unsigned long long)f2bf(S2[0][b])
          | ((unsigned long long)f2bf(S2[1][b]) << 16)
          | ((unsigned long long)f2bf(S2[2][b]) << 32)
          | ((unsigned long long)f2bf(S2[3][b]) << 48);
      __hip_atomic_store(reinterpret_cast<unsigned long long*>(
          &hp2nxt[((size_t)kg * 128 + bbase + b) * 8 + e0]), v,
          __ATOMIC_RELAXED, __HIP_MEMORY_SCOPE_AGENT);
    }

    if (p + 1 < T_ALL) gbar(bars, 2u + (unsigned)p, grp, wb);
  }
}

// ---------------- pack: h2seqT fp32 [t][u][b] -> h2b bf16 [t][u>>3][b][u&7] (MFMA-B layout) ----------------
__global__ __launch_bounds__(256) void k_pack(const float* __restrict__ h2seqT,
                                              ushort_* __restrict__ h2b) {
  __shared__ ushort_ Ls[128][8];
  const int tid = threadIdx.x;
  const int kg = blockIdx.x;          // 0..63
  const int t  = blockIdx.y;          // 0..26
  const int e  = tid >> 5;            // 0..7 (u & 7)
  const int b4 = tid & 31;            // b-quad
  f4x v = *reinterpret_cast<const f4x*>(&h2seqT[((size_t)t * HID_ + kg * 8 + e) * 128 + b4 * 4]);
#pragma unroll
  for (int j = 0; j < 4; ++j) Ls[b4 * 4 + j][e] = f2bf(v[j]);
  __syncthreads();
  if (tid < 128) {
    *reinterpret_cast<s8v*>(&h2b[(((size_t)t * 64 + kg) * 128 + tid) * 8]) =
        *reinterpret_cast<const s8v*>(&Ls[tid][0]);
  }
}

// ---------------- projection: bf16 MFMA, C[m=v][n=b] = Wb(16x32 A) x h2b(32x16 B) ----------------
__global__ __launch_bounds__(256) void k_proj(const ushort_* __restrict__ Wb,
                                              const ushort_* __restrict__ h2b,
                                              const float* __restrict__ bias,
                                              float* __restrict__ out) {
  __shared__ ushort_ As[128 * 40];
  const int tid = threadIdx.x;
  const int t  = blockIdx.x;
  const int v0 = blockIdx.y * 128;
  const int lane = tid & 63;
  const int l15 = lane & 15, l4 = lane >> 4;
  const int wm = (tid >> 6) & 1, wn = tid >> 7;

  f4x acc[4][4];
#pragma unroll
  for (int i = 0; i < 4; ++i)
#pragma unroll
    for (int j = 0; j < 4; ++j) acc[i][j] = (f4x){0.f, 0.f, 0.f, 0.f};

  const int c0 = tid * 2, c1 = c0 + 1;
  const int sv0 = c0 >> 2, sk0 = c0 & 3;
  const int sv1 = c1 >> 2, sk1 = c1 & 3;
  s8v r0, r1;
  r0 = *reinterpret_cast<const s8v*>(&Wb[(size_t)(v0 + sv0) * HID_ + sk0 * 8]);
  r1 = *reinterpret_cast<const s8v*>(&Wb[(size_t)(v0 + sv1) * HID_ + sk1 * 8]);

  for (int ks = 0; ks < 16; ++ks) {
    __syncthreads();
    *reinterpret_cast<s8v*>(&As[sv0 * 40 + sk0 * 8]) = r0;
    *reinterpret_cast<s8v*>(&As[sv1 * 40 + sk1 * 8]) = r1;
    __syncthreads();
    if (ks < 15) {
      r0 = *reinterpret_cast<const s8v*>(&Wb[(size_t)(v0 + sv0) * HID_ + (ks + 1) * 32 + sk0 * 8]);
      r1 = *reinterpret_cast<const s8v*>(&Wb[(size_t)(v0 + sv1) * HID_ + (ks + 1) * 32 + sk1 * 8]);
    }
    s8v a[4], b[4];
#pragma unroll
    for (int mt = 0; mt < 4; ++mt)
      a[mt] = *reinterpret_cast<const s8v*>(&As[(wm * 64 + mt * 16 + l15) * 40 + l4 * 8]);
#pragma unroll
    for (int nt = 0; nt < 4; ++nt)
      b[nt] = *reinterpret_cast<const s8v*>(
          &h2b[(((size_t)t * 64 + ks * 4 + l4) * 128 + wn * 64 + nt * 16 + l15) * 8]);
#pragma unroll
    for (int mt = 0; mt < 4; ++mt)
#pragma unroll
      for (int nt = 0; nt < 4; ++nt)
        acc[mt][nt] = __builtin_amdgcn_mfma_f32_16x16x32_bf16(a[mt], b[nt], acc[mt][nt], 0, 0, 0);
  }

#pragma unroll
  for (int mt = 0; mt < 4; ++mt) {
    const int vb = v0 + wm * 64 + mt * 16 + l4 * 4;
    float bv[4];
    if (vb + 3 < V_) {
      *reinterpret_cast<f4x*>(bv) = *reinterpret_cast<const f4x*>(&bias[vb]);
    } else {
#pragma unroll
      for (int r = 0; r < 4; ++r) bv[r] = (vb + r < V_) ? bias[vb + r] : 0.f;
    }
#pragma unroll
    for (int nt = 0; nt < 4; ++nt) {
      const int bc = wn * 64 + nt * 16 + l15;
      float* cp = &out[((size_t)bc * T_DEC + t) * V_ + vb];
      if (vb + 3 < V_) {
        f4x o = acc[mt][nt];
        o[0] += bv[0]; o[1] += bv[1]; o[2] += bv[2]; o[3] += bv[3];
        *reinterpret_cast<f4x*>(cp) = o;
      } else {
#pragma unroll
        for (int r = 0; r < 4; ++r) if (vb + r < V_) cp[r] = acc[mt][nt][r] + bv[r];
      }
    }
  }
}

// ---------------- log-softmax over rows of 20000 (in place on d_out), f4x vectorized ----------------
__global__ __launch_bounds__(256) void k_logsoftmax(float* __restrict__ out) {
  float* row = out + (size_t)blockIdx.x * V_;
  const int tid = threadIdx.x;
  float mx = -INFINITY, s = 0.f;
  for (int i = tid * 4; i < V_; i += 1024) {
    f4x x = *reinterpret_cast<const f4x*>(&row[i]);
#pragma unroll
    for (int j = 0; j < 4; ++j) {
      float v = x[j];
      if (v > mx) { s = s * expf(mx - v) + 1.f; mx = v; }
      else        { s += expf(v - mx); }
    }
  }
#pragma unroll
  for (int o = 1; o < 64; o <<= 1) {
    float omx = __shfl_xor(mx, o);
    float os  = __shfl_xor(s, o);
    float M = fmaxf(mx, omx);
    s = s * expf(mx - M) + os * expf(omx - M);
    mx = M;
  }
  __shared__ float smx[4], ss[4];
  int wid = tid >> 6, lane = tid & 63;
  if (lane == 0) { smx[wid] = mx; ss[wid] = s; }
  __syncthreads();
  if (tid == 0) {
    float M = smx[0]; float S = ss[0];
#pragma unroll
    for (int w = 1; w < 4; ++w) {
      float M2 = fmaxf(M, smx[w]);
      S = S * expf(M - M2) + ss[w] * expf(smx[w] - M2);
      M = M2;
    }
    ss[0] = logf(S) + M;
  }
  __syncthreads();
  float lse = ss[0];
  for (int i = tid * 4; i < V_; i += 1024) {
    f4x x = *reinterpret_cast<const f4x*>(&row[i]);
    x[0] -= lse; x[1] -= lse; x[2] -= lse; x[3] -= lse;
    *reinterpret_cast<f4x*>(&row[i]) = x;
  }
}

// ---------------- host launch ----------------
extern "C" void kernel_launch(void* const* d_in, const int* in_sizes, int n_in,
                              void* d_out, int out_size, void* d_ws, size_t ws_size,
                              hipStream_t stream) {
  const float* input = (const float*)d_in[0];
  const int*   target = (const int*)d_in[1];
  const float* W_ih1 = (const float*)d_in[2];
  const float* W_hh1 = (const float*)d_in[3];
  const float* b_ih1 = (const float*)d_in[4];
  const float* b_hh1 = (const float*)d_in[5];
  const float* W_ih2 = (const float*)d_in[6];
  const float* W_hh2 = (const float*)d_in[7];
  const float* b_ih2 = (const float*)d_in[8];
  const float* b_hh2 = (const float*)d_in[9];
  const float* E     = (const float*)d_in[10];
  const float* W_out = (const float*)d_in[11];
  const float* b_out = (const float*)d_in[12];
  float* out = (float*)d_out;

  float* ws = (float*)d_ws;
  float* G1t    = ws; ws += (size_t)T_ENC * G3_ * 128;           // [t][gate_row][b] fp32
  float* GWt    = ws; ws += (size_t)T_DEC * G3_ * 128;           // [t][gate_row][b] fp32
  ushort_* Wb   = (ushort_*)ws; ws += (size_t)20096 * HID_ / 2;  // bf16 W_out (padded rows)
  ushort_* h2b  = (ushort_*)ws; ws += (size_t)T_DEC * 64 * 128 * 8 / 2;  // bf16 [t][u>>3][b][u&7]
  float* h2seqT = ws; ws += (size_t)T_DEC * HID_ * 128;          // fp32 [t][u][b]
  ushort_* inb    = (ushort_*)ws; ws += (size_t)B_ * T_ENC * EMB_ / 2;   // bf16 input rows m=b*40+t
  ushort_* wordsb = (ushort_*)ws; ws += (size_t)B_ * T_DEC * HID_ / 2;   // bf16 words rows m=b*27+t
  ushort_* wih1b  = (ushort_*)ws; ws += (size_t)G3_ * EMB_ / 2;          // bf16 W_ih1
  ushort_* wih2b  = (ushort_*)ws; ws += (size_t)G3_ * EMB_ / 2;          // bf16 W_ih2
  // ---- contiguous memset region: hp2x (bf16 [64][128][8]) + bars (4 groups) ----
  ushort_* hp2x = (ushort_*)ws; ws += (size_t)64 * 128 * 8 / 2;
  unsigned* bars = (unsigned*)ws; ws += 1024;
  // ----
  ushort_* hp1x = (ushort_*)ws; ws += (size_t)64 * 128 * 8 / 2;
  ushort_* hp1y = (ushort_*)ws; ws += (size_t)64 * 128 * 8 / 2;
  ushort_* hp2y = (ushort_*)ws; ws += (size_t)64 * 128 * 8 / 2;

  hipMemsetAsync(hp2x, 0, (size_t)64 * 128 * 8 * 2 + 4096, stream);

  // converts (fp32 -> bf16)
  k_gather<<<B_ * T_DEC, 128, 0, stream>>>(target, E, wordsb);
  k_cvt<<<(B_ * T_ENC * EMB_) / 2048, 256, 0, stream>>>(input, inb);
  k_cvt<<<(G3_ * EMB_) / 2048, 256, 0, stream>>>(W_ih1, wih1b);
  k_cvt<<<(G3_ * EMB_) / 2048, 256, 0, stream>>>(W_ih2, wih2b);
  k_cvt<<<(V_ * HID_) / 2048, 256, 0, stream>>>(W_out, Wb);

  // prework gate GEMMs (bf16 MFMA, transposed scatter store)
  k_mm<<<dim3(12, (B_ * T_ENC) / 128), 256, 0, stream>>>(inb, EMB_, wih1b, EMB_, 0, b_ih1,
                                                         G1t, T_ENC, EMB_);
  k_mm<<<dim3(12, (B_ * T_DEC) / 128), 256, 0, stream>>>(wordsb, HID_, wih2b, EMB_, HID_, b_ih2,
                                                         GWt, T_DEC, HID_);

  k_recur<<<NBLK, 256, 0, stream>>>(G1t, GWt, W_hh1, W_ih2, W_hh2, b_hh1, b_hh2, b_ih1, b_ih2,
                                    hp1x, hp1y, hp2x, hp2y, h2seqT, bars);
  k_pack<<<dim3(64, T_DEC), 256, 0, stream>>>(h2seqT, h2b);

  k_proj<<<dim3(T_DEC, (V_ + 127) / 128), 256, 0, stream>>>(Wb, h2b, b_out, out);
  k_logsoftmax<<<B_ * T_DEC, 256, 0, stream>>>(out);
}